// Round 11
// baseline (1323.329 us; speedup 1.0000x reference)
//
#include <hip/hip_runtime.h>
#include <hip/hip_cooperative_groups.h>
#include <math.h>

namespace cg = cooperative_groups;

#define N_NODES 50000
#define E_EDGES 800000
#define HC 128
#define ED 32
#define SCH 64           // sort/scan chunks
#define SCHSZ 782        // ceil(N_NODES / SCH); 64*782 = 50048 >= 50000

typedef __attribute__((ext_vector_type(8))) short bf16x8;
typedef __attribute__((ext_vector_type(4))) float f32x4;
typedef unsigned short ushort_t;

__device__ __forceinline__ ushort_t f2bf(float f){
    unsigned u = __float_as_uint(f);
    return (ushort_t)((u + 0x7FFFu + ((u >> 16) & 1u)) >> 16);   // RNE
}
__device__ __forceinline__ float bflo(unsigned u){ return __uint_as_float(u << 16); }
__device__ __forceinline__ float bfhi(unsigned u){ return __uint_as_float(u & 0xffff0000u); }

// WeT layout: stride 40, per-row quad-rotation. BIJECTIVE, float4-aligned,
// read bank-quad spread -> <=2-way (free). Verified correct in R4.
__device__ __forceinline__ int weidx(int c, int d){
    return c * 40 + (((((d >> 2) + ((c >> 3) & 7)) & 7)) << 2) + (d & 3);
}

// ================= cooperative CSR build (replaces 5 dispatches) =================
// phases separated by grid.sync(): zero -> hist -> chunk-hist/csum ->
// rowptr/cursor fill -> edge scatter + DESCENDING degree sort (LPT: heavy
// attn blocks dispatch first, light blocks pack the drain tail -- R10's 26%
// occupancy was the ascending order draining on the heaviest blocks).
__global__ __launch_bounds__(256) void csr_build_kernel(
    const int* __restrict__ src, const int* __restrict__ dst,
    int* __restrict__ cnt, int* __restrict__ rowptr, int* __restrict__ cursor,
    int* __restrict__ chist, int* __restrict__ csum,
    int2* __restrict__ es, int* __restrict__ norder)
{
    cg::grid_group grid = cg::this_grid();
    __shared__ int sA[256];
    __shared__ int sB[64];
    __shared__ int sC[64];
    __shared__ int sD[64];
    __shared__ int sE[64];
    __shared__ int sBase;
    const int t = threadIdx.x, b = blockIdx.x;
    const int gt = b * 256 + t, gs = gridDim.x * 256;

    // ---- phase 0: zero cnt ----
    for (int i = gt; i < N_NODES; i += gs) cnt[i] = 0;
    grid.sync();

    // ---- phase 1: degree histogram ----
    for (int e = gt; e < E_EDGES; e += gs) atomicAdd(&cnt[dst[e]], 1);
    grid.sync();

    // ---- phase 2a: blocks 0..SCH-1: chunk degree-histogram + chunk edge-sum ----
    if (b < SCH){
        if (t < 64) sB[t] = 0;
        __syncthreads();
        const int base = b * SCHSZ;
        const int lim = min(base + SCHSZ, N_NODES);
        int mysum = 0;
        for (int i = base + t; i < lim; i += 256){
            int d = cnt[i]; mysum += d;
            if (d > 63) d = 63;
            atomicAdd(&sB[d], 1);
        }
        sA[t] = mysum;
        __syncthreads();
        for (int off = 128; off; off >>= 1){
            if (t < off) sA[t] += sA[t + off];
            __syncthreads();
        }
        if (t < 64) chist[b * 64 + t] = sB[t];
        if (t == 0) csum[b] = sA[0];
    }
    grid.sync();

    // ---- phase 2b: blocks 0..SCH-1: rowptr/cursor fill ----
    if (b < SCH){
        if (t == 0){
            int acc = 0;
            for (int c = 0; c < b; c++) acc += csum[c];
            sBase = acc;
        }
        const int base = b * SCHSZ;
        const int lim = min(base + SCHSZ, N_NODES);
        const int idx0 = base + t * 4;          // 256*4 = 1024 >= SCHSZ
        int c4[4]; int local = 0;
        #pragma unroll
        for (int j = 0; j < 4; j++){
            int idx = idx0 + j;
            c4[j] = (idx < lim) ? cnt[idx] : 0;
            local += c4[j];
        }
        sA[t] = local;
        __syncthreads();                         // also orders sBase write before reads
        for (int off = 1; off < 256; off <<= 1){
            int v = (t >= off) ? sA[t - off] : 0;
            __syncthreads();
            sA[t] += v;
            __syncthreads();
        }
        int off0 = sBase + ((t == 0) ? 0 : sA[t - 1]);
        #pragma unroll
        for (int j = 0; j < 4; j++){
            int idx = idx0 + j;
            if (idx < lim){
                rowptr[idx] = off0; cursor[idx] = off0;
                off0 += c4[j];
            }
        }
        if (b == SCH - 1 && t == 255) rowptr[N_NODES] = sBase + sA[255];
    }
    grid.sync();

    // ---- phase 3: edge scatter (all blocks) + node sort (blocks 0..SCH-1) ----
    if (b < SCH){
        if (t < 64){
            int tot = 0, pre = 0;
            for (int c = 0; c < SCH; c++){
                int v = chist[c * 64 + t];
                tot += v;
                if (c < b) pre += v;
            }
            sB[t] = tot; sE[t] = pre;
        }
        __syncthreads();
        if (t == 0){
            int a = 0;
            for (int d = 0; d < 64; d++){ int v = sB[d]; sC[d] = a; a += v; }
        }
        __syncthreads();
        if (t < 64) sD[t] = sC[t] + sE[t];
        __syncthreads();
    }
    for (int e = gt; e < E_EDGES; e += gs){
        int d = dst[e];
        int pos = atomicAdd(&cursor[d], 1);
        es[pos] = make_int2(e, src[e]);
    }
    if (b < SCH){
        const int base = b * SCHSZ;
        const int lim = min(base + SCHSZ, N_NODES);
        for (int i = base + t; i < lim; i += 256){
            int d = cnt[i]; if (d > 63) d = 63;
            int pos = atomicAdd(&sD[d], 1);
            norder[N_NODES - 1 - pos] = i;   // DESCENDING degree (LPT schedule)
        }
    }
}

// ============== fused tail: permute_attr + x->bf16 + pack 3 layers (+Wqe fold, qwb) ==============
__device__ __forceinline__ void pack_item(const float* __restrict__ Wq, const float* __restrict__ Wk,
                                          const float* __restrict__ Wv, const float* __restrict__ Ws,
                                          const float* __restrict__ We, ushort_t* __restrict__ Bp,
                                          int K, int item){
    int n = item % 640, k = item / 640;
    float val;
    if (n < 512){
        const float* W = (n < 128) ? Wq : (n < 256) ? Wk : (n < 384) ? Wv : Ws;
        val = W[k * HC + (n & 127)];
    } else {
        int col = n - 512, h5 = (col >> 5) * 32, d = col & 31;
        float acc = 0.f;
        for (int c = 0; c < 32; c++)
            acc = fmaf(Wq[k * HC + h5 + c], We[d * HC + h5 + c], acc);
        val = acc;
    }
    Bp[(((size_t)(k >> 3)) * 640 + n) * 8 + (k & 7)] = f2bf(val);
}

#define T_S0 12800000            // permute_attr items (E*16)
#define T_S1 16000000            // + convert items (N*256/4)
#define T_S2 16163840            // + pack L0 (256*640)
#define T_S3 16245760            // + pack L1 (128*640)
#define T_S4 16327680            // + pack L2 (128*640)
#define T_S5 16328064            // + qwb (3*128)

__global__ __launch_bounds__(256) void tail_kernel(
    const float* __restrict__ attr, const int2* __restrict__ es,
    const float* __restrict__ x, int perm_mode,
    ushort_t* __restrict__ attr_bf, ushort_t* __restrict__ Xbf,
    const float* __restrict__ Wq0, const float* __restrict__ bq0, const float* __restrict__ Wk0,
    const float* __restrict__ Wv0, const float* __restrict__ Ws0, const float* __restrict__ We0,
    const float* __restrict__ Wq1, const float* __restrict__ bq1, const float* __restrict__ Wk1,
    const float* __restrict__ Wv1, const float* __restrict__ Ws1, const float* __restrict__ We1,
    const float* __restrict__ Wq2, const float* __restrict__ bq2, const float* __restrict__ Wk2,
    const float* __restrict__ Wv2, const float* __restrict__ Ws2, const float* __restrict__ We2,
    ushort_t* __restrict__ Bp0, ushort_t* __restrict__ Bp1, ushort_t* __restrict__ Bp2,
    float* __restrict__ qwb3)
{
    const int stride = gridDim.x * blockDim.x;
    for (int gi = blockIdx.x * blockDim.x + threadIdx.x; gi < T_S5; gi += stride){
        if (gi < T_S0){
            if (perm_mode){
                int grp = gi >> 4, lane = gi & 15;
                int e = es[grp].x;
                const float2 v = *(const float2*)&attr[(size_t)e * ED + lane * 2];
                unsigned r = (unsigned)f2bf(v.x) | ((unsigned)f2bf(v.y) << 16);
                ((unsigned*)attr_bf)[(size_t)grp * (ED / 2) + lane] = r;
            }
        } else if (gi < T_S1){
            int i = gi - T_S0;
            float4 v = ((const float4*)x)[i];
            ushort_t r0 = f2bf(v.x), r1 = f2bf(v.y), r2 = f2bf(v.z), r3 = f2bf(v.w);
            ((ushort4*)Xbf)[i] = make_ushort4(r0, r1, r2, r3);
        } else if (gi < T_S2){
            pack_item(Wq0, Wk0, Wv0, Ws0, We0, Bp0, 256, gi - T_S1);
        } else if (gi < T_S3){
            pack_item(Wq1, Wk1, Wv1, Ws1, We1, Bp1, 128, gi - T_S2);
        } else if (gi < T_S4){
            pack_item(Wq2, Wk2, Wv2, Ws2, We2, Bp2, 128, gi - T_S3);
        } else {
            int f = gi - T_S4;
            int l = f >> 7, t2 = f & 127;
            const float* bq = (l == 0) ? bq0 : (l == 1) ? bq1 : bq2;
            const float* We = (l == 0) ? We0 : (l == 1) ? We1 : We2;
            int h5 = (t2 >> 5) * 32, d = t2 & 31;
            float acc = 0.f;
            for (int c = 0; c < 32; c++)
                acc = fmaf(bq[h5 + c], We[d * HC + h5 + c], acc);
            qwb3[l * HC + t2] = acc;
        }
    }
}

// ===================== MFMA GEMM: [M,K]bf16 @ [K,640]bf16 + bias ====
template<int K>
__global__ __launch_bounds__(320) void gemm_mfma(
    const ushort_t* __restrict__ Xbf, const ushort_t* __restrict__ Bpack,
    const float* __restrict__ b0, const float* __restrict__ b1,
    const float* __restrict__ b2, const float* __restrict__ b3,
    const float* __restrict__ b4,
    float* __restrict__ Yq, ushort_t* __restrict__ Ykbf,
    ushort_t* __restrict__ Yvbf, float* __restrict__ Ys,
    float* __restrict__ Yw, int M)
{
    const int w = threadIdx.x >> 6;
    const int lane = threadIdx.x & 63;
    const int q = lane >> 4, nn = lane & 15;
    const int row0 = blockIdx.x * 32;

    f32x4 acc[2][8];
    #pragma unroll
    for (int mt = 0; mt < 2; mt++)
        #pragma unroll
        for (int nt = 0; nt < 8; nt++)
            acc[mt][nt] = (f32x4){0.f, 0.f, 0.f, 0.f};

    const int r0 = row0 + nn;
    const int r1 = row0 + 16 + nn;
    const bf16x8 zf = (bf16x8){0,0,0,0,0,0,0,0};

    #pragma unroll
    for (int kc = 0; kc < K / 32; kc++){
        bf16x8 a0 = (r0 < M) ? *(const bf16x8*)&Xbf[(size_t)r0 * K + kc * 32 + q * 8] : zf;
        bf16x8 a1 = (r1 < M) ? *(const bf16x8*)&Xbf[(size_t)r1 * K + kc * 32 + q * 8] : zf;
        bf16x8 b[8];
        #pragma unroll
        for (int nt = 0; nt < 8; nt++){
            int n = w * 128 + nt * 16 + nn;
            b[nt] = *(const bf16x8*)&Bpack[(((size_t)(kc * 4 + q)) * 640 + n) * 8];
        }
        #pragma unroll
        for (int nt = 0; nt < 8; nt++){
            acc[0][nt] = __builtin_amdgcn_mfma_f32_16x16x32_bf16(a0, b[nt], acc[0][nt], 0, 0, 0);
            acc[1][nt] = __builtin_amdgcn_mfma_f32_16x16x32_bf16(a1, b[nt], acc[1][nt], 0, 0, 0);
        }
    }

    const float scale = (w == 0 || w == 4) ? 0.17677669529663687f : 1.f;
    const float* bias = (w == 0) ? b0 : (w == 1) ? b1 : (w == 2) ? b2 : (w == 3) ? b3 : b4;

    if (w == 1 || w == 2){
        ushort_t* Yb = (w == 1) ? Ykbf : Yvbf;
        #pragma unroll
        for (int nt = 0; nt < 8; nt++){
            int col = nt * 16 + nn;
            float bval = bias[col];
            #pragma unroll
            for (int mt = 0; mt < 2; mt++){
                #pragma unroll
                for (int r = 0; r < 4; r++){
                    int row = row0 + mt * 16 + q * 4 + r;
                    if (row < M) Yb[(size_t)row * HC + col] = f2bf(acc[mt][nt][r] + bval);
                }
            }
        }
    } else {
        float* Y = (w == 0) ? Yq : (w == 3) ? Ys : Yw;
        #pragma unroll
        for (int nt = 0; nt < 8; nt++){
            int col = nt * 16 + nn;
            float bval = bias[col];
            #pragma unroll
            for (int mt = 0; mt < 2; mt++){
                #pragma unroll
                for (int r = 0; r < 4; r++){
                    int row = row0 + mt * 16 + q * 4 + r;
                    if (row < M) Y[(size_t)row * HC + col] = (acc[mt][nt][r] + bval) * scale;
                }
            }
        }
    }
}

// ===================== fused per-node attention (unchanged from R10) =====================
__device__ __forceinline__ float dot16s(const uint4 kk, const uint4 aa,
                                        const float4 qA, const float4 qB,
                                        const float4 wA, const float4 wB){
    float pa =            bflo(kk.x) * qA.x;
    pa = fmaf(bfhi(kk.x), qA.y, pa);
    pa = fmaf(bflo(kk.y), qA.z, pa);
    pa = fmaf(bfhi(kk.y), qA.w, pa);
    pa = fmaf(bflo(aa.x), wA.x, pa);
    pa = fmaf(bfhi(aa.x), wA.y, pa);
    pa = fmaf(bflo(aa.y), wA.z, pa);
    pa = fmaf(bfhi(aa.y), wA.w, pa);
    float pb =            bflo(kk.z) * qB.x;
    pb = fmaf(bfhi(kk.z), qB.y, pb);
    pb = fmaf(bflo(kk.w), qB.z, pb);
    pb = fmaf(bfhi(kk.w), qB.w, pb);
    pb = fmaf(bflo(aa.z), wB.x, pb);
    pb = fmaf(bfhi(aa.z), wB.y, pb);
    pb = fmaf(bflo(aa.w), wB.z, pb);
    pb = fmaf(bfhi(aa.w), wB.w, pb);
    return pa + pb;
}

__device__ __forceinline__ uint4 packrow(const float* p){
    float4 x = *(const float4*)p;
    float4 y = *(const float4*)(p + 4);
    uint4 r;
    r.x = (unsigned)f2bf(x.x) | ((unsigned)f2bf(x.y) << 16);
    r.y = (unsigned)f2bf(x.z) | ((unsigned)f2bf(x.w) << 16);
    r.z = (unsigned)f2bf(y.x) | ((unsigned)f2bf(y.y) << 16);
    r.w = (unsigned)f2bf(y.z) | ((unsigned)f2bf(y.w) << 16);
    return r;
}

__global__ __launch_bounds__(256) void fused_attn_kernel(
    const float* __restrict__ qs, const float* __restrict__ qw,
    const ushort_t* __restrict__ kb, const ushort_t* __restrict__ vb,
    const float* __restrict__ skip, const float* __restrict__ We,
    const float* __restrict__ attr, const ushort_t* __restrict__ attr_bf, int perm_mode,
    const int* __restrict__ rowptr, const int2* __restrict__ es,
    const int* __restrict__ norder,
    float* __restrict__ acsr, float* __restrict__ a_out,
    const float* __restrict__ g, const float* __restrict__ be,
    float* __restrict__ out_f32, ushort_t* __restrict__ out_bf, int apply_ln)
{
    __shared__ float WeT[5120];         // 128 rows x stride 40 (bijective quad-rotated) f32
    __shared__ float SL[2304];          // 16 nodes x 144
    const int t = threadIdx.x;
    for (int idx = t; idx < ED * HC; idx += 256){
        int d = idx >> 7, c = idx & 127;
        WeT[weidx(c, d)] = We[idx];
    }
    __syncthreads();

    const int lane = t & 63, wvi = t >> 6;
    const int qq = lane >> 4, li = lane & 15;
    const int h = li >> 2, jj = li & 3;
    const int gq = blockIdx.x * 16 + wvi * 4 + qq;
    if (gq >= N_NODES) return;
    const int n = norder[gq];
    const int ch = h * 32 + jj * 8;
    const size_t nrow = (size_t)n * HC + ch;

    const float4 qA = *(const float4*)&qs[nrow];
    const float4 qB = *(const float4*)&qs[nrow + 4];
    const float4 wA = *(const float4*)&qw[nrow];
    const float4 wB = *(const float4*)&qw[nrow + 4];
    const float4 skA = *(const float4*)&skip[nrow];
    const float4 skB = *(const float4*)&skip[nrow + 4];

    const int beg = rowptr[n], end = rowptr[n + 1];
    float m = -1e30f, s = 0.f;
    float acc[8] = {0,0,0,0,0,0,0,0};
    float S[8]   = {0,0,0,0,0,0,0,0};

    for (int i = beg; i < end; i += 4){
        const int cnt = end - i;
        uint4 kk[4], vv[4], aa[4];
        #pragma unroll
        for (int b = 0; b < 4; b++){
            kk[b] = (uint4){0,0,0,0}; vv[b] = (uint4){0,0,0,0}; aa[b] = (uint4){0,0,0,0};
            if (b < cnt){
                const int2 e = es[i + b];
                kk[b] = *(const uint4*)&kb[(size_t)e.y * HC + ch];
                vv[b] = *(const uint4*)&vb[(size_t)e.y * HC + ch];
                if (perm_mode)
                    aa[b] = *(const uint4*)&attr_bf[(size_t)(i + b) * ED + jj * 8];
                else
                    aa[b] = packrow(&attr[(size_t)e.x * ED + jj * 8]);
            }
        }
        float al[4];
        #pragma unroll
        for (int b = 0; b < 4; b++){
            float p = dot16s(kk[b], aa[b], qA, qB, wA, wB);
            p += __shfl_xor(p, 1);
            p += __shfl_xor(p, 2);
            al[b] = (b < cnt) ? p : -1e38f;
        }
        if (jj == 0){
            #pragma unroll
            for (int b = 0; b < 4; b++)
                if (b < cnt) acsr[(size_t)(i + b) * 4 + h] = al[b];
        }
        const float mn = fmaxf(fmaxf(m, fmaxf(al[0], al[1])), fmaxf(al[2], al[3]));
        const float sc = __expf(m - mn);
        m = mn;
        const float w0 = __expf(al[0] - mn);
        const float w1 = __expf(al[1] - mn);
        const float w2 = __expf(al[2] - mn);
        const float w3 = __expf(al[3] - mn);
        s = fmaf(s, sc, (w0 + w1) + (w2 + w3));
        acc[0] = fmaf(acc[0], sc, fmaf(w0, bflo(vv[0].x), fmaf(w1, bflo(vv[1].x), fmaf(w2, bflo(vv[2].x), w3 * bflo(vv[3].x)))));
        acc[1] = fmaf(acc[1], sc, fmaf(w0, bfhi(vv[0].x), fmaf(w1, bfhi(vv[1].x), fmaf(w2, bfhi(vv[2].x), w3 * bfhi(vv[3].x)))));
        acc[2] = fmaf(acc[2], sc, fmaf(w0, bflo(vv[0].y), fmaf(w1, bflo(vv[1].y), fmaf(w2, bflo(vv[2].y), w3 * bflo(vv[3].y)))));
        acc[3] = fmaf(acc[3], sc, fmaf(w0, bfhi(vv[0].y), fmaf(w1, bfhi(vv[1].y), fmaf(w2, bfhi(vv[2].y), w3 * bfhi(vv[3].y)))));
        acc[4] = fmaf(acc[4], sc, fmaf(w0, bflo(vv[0].z), fmaf(w1, bflo(vv[1].z), fmaf(w2, bflo(vv[2].z), w3 * bflo(vv[3].z)))));
        acc[5] = fmaf(acc[5], sc, fmaf(w0, bfhi(vv[0].z), fmaf(w1, bfhi(vv[1].z), fmaf(w2, bfhi(vv[2].z), w3 * bfhi(vv[3].z)))));
        acc[6] = fmaf(acc[6], sc, fmaf(w0, bflo(vv[0].w), fmaf(w1, bflo(vv[1].w), fmaf(w2, bflo(vv[2].w), w3 * bflo(vv[3].w)))));
        acc[7] = fmaf(acc[7], sc, fmaf(w0, bfhi(vv[0].w), fmaf(w1, bfhi(vv[1].w), fmaf(w2, bfhi(vv[2].w), w3 * bfhi(vv[3].w)))));
        S[0] = fmaf(S[0], sc, fmaf(w0, bflo(aa[0].x), fmaf(w1, bflo(aa[1].x), fmaf(w2, bflo(aa[2].x), w3 * bflo(aa[3].x)))));
        S[1] = fmaf(S[1], sc, fmaf(w0, bfhi(aa[0].x), fmaf(w1, bfhi(aa[1].x), fmaf(w2, bfhi(aa[2].x), w3 * bfhi(aa[3].x)))));
        S[2] = fmaf(S[2], sc, fmaf(w0, bflo(aa[0].y), fmaf(w1, bflo(aa[1].y), fmaf(w2, bflo(aa[2].y), w3 * bflo(aa[3].y)))));
        S[3] = fmaf(S[3], sc, fmaf(w0, bfhi(aa[0].y), fmaf(w1, bfhi(aa[1].y), fmaf(w2, bfhi(aa[2].y), w3 * bfhi(aa[3].y)))));
        S[4] = fmaf(S[4], sc, fmaf(w0, bflo(aa[0].z), fmaf(w1, bflo(aa[1].z), fmaf(w2, bflo(aa[2].z), w3 * bflo(aa[3].z)))));
        S[5] = fmaf(S[5], sc, fmaf(w0, bfhi(aa[0].z), fmaf(w1, bfhi(aa[1].z), fmaf(w2, bfhi(aa[2].z), w3 * bfhi(aa[3].z)))));
        S[6] = fmaf(S[6], sc, fmaf(w0, bflo(aa[0].w), fmaf(w1, bflo(aa[1].w), fmaf(w2, bflo(aa[2].w), w3 * bflo(aa[3].w)))));
        S[7] = fmaf(S[7], sc, fmaf(w0, bfhi(aa[0].w), fmaf(w1, bfhi(aa[1].w), fmaf(w2, bfhi(aa[2].w), w3 * bfhi(aa[3].w)))));
    }

    // ---- E = We_h^T S_h via per-node LDS transpose ----
    const int nl = wvi * 4 + qq;
    const int sbase = nl * 144;
    const int hsk = h * 36;
    *(float4*)&SL[sbase + hsk + jj * 8]     = make_float4(S[0], S[1], S[2], S[3]);
    *(float4*)&SL[sbase + hsk + jj * 8 + 4] = make_float4(S[4], S[5], S[6], S[7]);
    asm volatile("" ::: "memory");     // in-wave LDS write->read ordering
    float E[8] = {0,0,0,0,0,0,0,0};
    #pragma unroll
    for (int d4 = 0; d4 < 8; d4++){
        const float4 sv = *(const float4*)&SL[sbase + hsk + d4 * 4];
        #pragma unroll
        for (int r = 0; r < 8; r++){
            const float4 wv = *(const float4*)&WeT[weidx(ch + r, d4 * 4)];
            E[r] = fmaf(sv.x, wv.x, fmaf(sv.y, wv.y, fmaf(sv.z, wv.z, fmaf(sv.w, wv.w, E[r]))));
        }
    }

    const float inv = 1.f / (s + 1e-16f);
    float o[8];
    o[0] = (acc[0] + E[0]) * inv + skA.x;
    o[1] = (acc[1] + E[1]) * inv + skA.y;
    o[2] = (acc[2] + E[2]) * inv + skA.z;
    o[3] = (acc[3] + E[3]) * inv + skA.w;
    o[4] = (acc[4] + E[4]) * inv + skB.x;
    o[5] = (acc[5] + E[5]) * inv + skB.y;
    o[6] = (acc[6] + E[6]) * inv + skB.z;
    o[7] = (acc[7] + E[7]) * inv + skB.w;

    if (apply_ln){
        float s1 = 0.f, s2 = 0.f;
        #pragma unroll
        for (int r = 0; r < 8; r++){ s1 += o[r]; s2 = fmaf(o[r], o[r], s2); }
        #pragma unroll
        for (int off = 1; off <= 8; off <<= 1){
            s1 += __shfl_xor(s1, off);
            s2 += __shfl_xor(s2, off);
        }
        const float mu  = s1 * (1.f / 128.f);
        const float var = s2 * (1.f / 128.f) - mu * mu;
        const float ivs = rsqrtf(var + 1e-5f);
        const float4 gA = *(const float4*)&g[ch];
        const float4 gB = *(const float4*)&g[ch + 4];
        const float4 bA = *(const float4*)&be[ch];
        const float4 bB = *(const float4*)&be[ch + 4];
        o[0] = fmaxf((o[0] - mu) * ivs * gA.x + bA.x, 0.f);
        o[1] = fmaxf((o[1] - mu) * ivs * gA.y + bA.y, 0.f);
        o[2] = fmaxf((o[2] - mu) * ivs * gA.z + bA.z, 0.f);
        o[3] = fmaxf((o[3] - mu) * ivs * gA.w + bA.w, 0.f);
        o[4] = fmaxf((o[4] - mu) * ivs * gB.x + bB.x, 0.f);
        o[5] = fmaxf((o[5] - mu) * ivs * gB.y + bB.y, 0.f);
        o[6] = fmaxf((o[6] - mu) * ivs * gB.z + bB.z, 0.f);
        o[7] = fmaxf((o[7] - mu) * ivs * gB.w + bB.w, 0.f);
        uint4 st;
        st.x = (unsigned)f2bf(o[0]) | ((unsigned)f2bf(o[1]) << 16);
        st.y = (unsigned)f2bf(o[2]) | ((unsigned)f2bf(o[3]) << 16);
        st.z = (unsigned)f2bf(o[4]) | ((unsigned)f2bf(o[5]) << 16);
        st.w = (unsigned)f2bf(o[6]) | ((unsigned)f2bf(o[7]) << 16);
        *(uint4*)&out_bf[nrow] = st;
    } else {
        *(float4*)&out_f32[nrow]     = make_float4(o[0], o[1], o[2], o[3]);
        *(float4*)&out_f32[nrow + 4] = make_float4(o[4], o[5], o[6], o[7]);
    }

    // ---- fused norm_a ----
    const float mh = __shfl(m, (qq << 4) + ((li & 3) << 2));
    const float dh = __shfl(s, (qq << 4) + ((li & 3) << 2));
    const float ih = 1.f / (dh + 1e-16f);
    asm volatile("s_waitcnt vmcnt(0)" ::: "memory");   // our acsr stores visible
    for (int f = beg * 4 + li; f < end * 4; f += 16){
        const int e = es[f >> 2].x;
        a_out[(size_t)e * 4 + (li & 3)] = __expf(acsr[f] - mh) * ih;
    }
}

// ============================ launch ============================

extern "C" void kernel_launch(void* const* d_in, const int* in_sizes, int n_in,
                              void* d_out, int out_size, void* d_ws, size_t ws_size,
                              hipStream_t stream) {
    const float* x    = (const float*)d_in[0];
    const int*   ei   = (const int*)  d_in[1];
    const float* attr = (const float*)d_in[2];
    const float* gln[2]  = { (const float*)d_in[30], (const float*)d_in[32] };
    const float* beln[2] = { (const float*)d_in[31], (const float*)d_in[33] };

    float* out   = (float*)d_out;
    float* h_out = out;
    float* a_out[3] = { out + (size_t)N_NODES * HC,
                        out + (size_t)N_NODES * HC + (size_t)E_EDGES * 4,
                        out + (size_t)N_NODES * HC + (size_t)2 * E_EDGES * 4 };

    // ---- workspace layout (64B-aligned chunks); attr_bf LAST (perm-gated) ----
    char* base = (char*)d_ws;
    size_t off = 0;
    auto alloc = [&](size_t bytes) -> void* {
        void* p = base + off;
        off = (off + bytes + 63) & ~(size_t)63;
        return p;
    };
    const size_t NB = (size_t)N_NODES * HC;
    float* qbuf     = (float*)alloc(NB * 4);
    float* qwbuf    = (float*)alloc(NB * 4);
    ushort_t* kbf   = (ushort_t*)alloc(NB * 2);
    ushort_t* vbf   = (ushort_t*)alloc(NB * 2);
    float* sbuf     = (float*)alloc(NB * 4);
    int* rowptr     = (int*)alloc((N_NODES + 1) * 4);
    int* cnt        = (int*)alloc(N_NODES * 4);
    int* cursor     = (int*)alloc(N_NODES * 4);
    int* norder     = (int*)alloc(N_NODES * 4);
    int* chist      = (int*)alloc(SCH * 64 * 4);
    int* csum       = (int*)alloc(SCH * 4);
    int2* es        = (int2*)alloc((size_t)E_EDGES * 8);
    ushort_t* Xbf   = (ushort_t*)alloc((size_t)N_NODES * 256 * 2);
    ushort_t* Hbf   = (ushort_t*)alloc(NB * 2);
    ushort_t* Bp0   = (ushort_t*)alloc((size_t)256 * 640 * 2);
    ushort_t* Bp1   = (ushort_t*)alloc((size_t)128 * 640 * 2);
    ushort_t* Bp2   = (ushort_t*)alloc((size_t)128 * 640 * 2);
    float* acsr     = (float*)alloc((size_t)E_EDGES * 4 * 4);
    float* qwb3     = (float*)alloc((size_t)3 * HC * 4);
    ushort_t* attr_bf = (ushort_t*)alloc((size_t)E_EDGES * ED * 2);
    const int perm_mode = (ws_size >= off) ? 1 : 0;

    const int* srcp = ei;
    const int* dstp = ei + E_EDGES;

    // ---- prep: 1 cooperative CSR-build + 1 tail (was 1 memset + 5 kernels) ----
    {
        void* args[] = { (void*)&srcp, (void*)&dstp, (void*)&cnt, (void*)&rowptr,
                         (void*)&cursor, (void*)&chist, (void*)&csum,
                         (void*)&es, (void*)&norder };
        hipLaunchCooperativeKernel((const void*)csr_build_kernel,
                                   dim3(1024), dim3(256), args, 0, stream);
    }
    tail_kernel<<<4096, 256, 0, stream>>>(
        attr, es, x, perm_mode, attr_bf, Xbf,
        (const float*)d_in[3],  (const float*)d_in[4],  (const float*)d_in[5],
        (const float*)d_in[7],  (const float*)d_in[10], (const float*)d_in[9],
        (const float*)d_in[12], (const float*)d_in[13], (const float*)d_in[14],
        (const float*)d_in[16], (const float*)d_in[19], (const float*)d_in[18],
        (const float*)d_in[21], (const float*)d_in[22], (const float*)d_in[23],
        (const float*)d_in[25], (const float*)d_in[28], (const float*)d_in[27],
        Bp0, Bp1, Bp2, qwb3);

    const int gemm_grid = (N_NODES + 31) / 32;
    const int attn_grid = (N_NODES + 15) / 16;
    ushort_t* Bps[3] = { Bp0, Bp1, Bp2 };

    for (int l = 0; l < 3; l++){
        const float* bq = (const float*)d_in[3 + 9 * l + 1];
        const float* bk = (const float*)d_in[3 + 9 * l + 3];
        const float* bv = (const float*)d_in[3 + 9 * l + 5];
        const float* We = (const float*)d_in[3 + 9 * l + 6];
        const float* bs = (const float*)d_in[3 + 9 * l + 8];

        if (l == 0)
            gemm_mfma<256><<<gemm_grid, 320, 0, stream>>>(Xbf, Bps[l], bq, bk, bv, bs, qwb3 + 128 * l,
                                                          qbuf, kbf, vbf, sbuf, qwbuf, N_NODES);
        else
            gemm_mfma<128><<<gemm_grid, 320, 0, stream>>>(Hbf, Bps[l], bq, bk, bv, bs, qwb3 + 128 * l,
                                                          qbuf, kbf, vbf, sbuf, qwbuf, N_NODES);

        const float* gg = (l < 2) ? gln[l] : nullptr;
        const float* bb = (l < 2) ? beln[l] : nullptr;
        fused_attn_kernel<<<attn_grid, 256, 0, stream>>>(
            qbuf, qwbuf, kbf, vbf, sbuf, We, attr, attr_bf, perm_mode,
            rowptr, es, norder, acsr, a_out[l], gg, bb,
            (l < 2) ? nullptr : h_out, (l < 2) ? Hbf : nullptr, (l < 2) ? 1 : 0);
    }
}

// Round 13
// 938.093 us; speedup vs baseline: 1.4107x; 1.4107x over previous
//
#include <hip/hip_runtime.h>
#include <math.h>

#define N_NODES 50000
#define E_EDGES 800000
#define HC 128
#define ED 32
#define SCH 64           // sort/scan chunks (one block each)
#define SCHSZ 782        // ceil(N_NODES / SCH); 64*782 = 50048 >= 50000

typedef __attribute__((ext_vector_type(8))) short bf16x8;
typedef __attribute__((ext_vector_type(4))) float f32x4;
typedef unsigned short ushort_t;

__device__ __forceinline__ ushort_t f2bf(float f){
    unsigned u = __float_as_uint(f);
    return (ushort_t)((u + 0x7FFFu + ((u >> 16) & 1u)) >> 16);   // RNE
}
__device__ __forceinline__ float bflo(unsigned u){ return __uint_as_float(u << 16); }
__device__ __forceinline__ float bfhi(unsigned u){ return __uint_as_float(u & 0xffff0000u); }

// WeT layout: stride 40, per-row quad-rotation. BIJECTIVE, float4-aligned,
// read bank-quad spread -> <=2-way (free). Verified correct in R4.
__device__ __forceinline__ int weidx(int c, int d){
    return c * 40 + (((((d >> 2) + ((c >> 3) & 7)) & 7)) << 2) + (d & 3);
}

// ============================ CSR build ============================
// R11: cooperative grid.sync() @1024 blocks ~100us each -> 5 small dispatches win.
// R12: descending (LPT) norder failed the replay-divergence tripwire; ascending
// (this version, R10) passed. Scheduling-order changes move attn <=10% anyway
// (R5-R7 evidence) -- keep the verified ascending order.

__global__ void hist_kernel(const int* __restrict__ dst, int* __restrict__ cnt, int n_edges){
    int e = blockIdx.x * blockDim.x + threadIdx.x;
    if (e < n_edges) atomicAdd(&cnt[dst[e]], 1);
}

// per-chunk degree histogram + per-chunk edge total (64 blocks).
__global__ __launch_bounds__(256) void chunk_hist_kernel(const int* __restrict__ cnt,
                                                         int* __restrict__ chist,
                                                         int* __restrict__ csum){
    __shared__ int hist[64];
    __shared__ int red[256];
    const int t = threadIdx.x, b = blockIdx.x;
    if (t < 64) hist[t] = 0;
    __syncthreads();
    const int base = b * SCHSZ;
    const int lim = min(base + SCHSZ, N_NODES);
    int mysum = 0;
    for (int i = base + t; i < lim; i += 256){
        int d = cnt[i];
        mysum += d;
        if (d > 63) d = 63;
        atomicAdd(&hist[d], 1);
    }
    red[t] = mysum;
    __syncthreads();
    for (int off = 128; off; off >>= 1){
        if (t < off) red[t] += red[t + off];
        __syncthreads();
    }
    if (t < 64) chist[b * 64 + t] = hist[t];
    if (t == 0) csum[b] = red[0];
}

// 64 blocks: each block prefixes csum for its chunk base, then block-scans its
// 782 node degrees -> rowptr/cursor.
__global__ __launch_bounds__(256) void fill_rowptr_kernel(
    const int* __restrict__ cnt, const int* __restrict__ csum,
    int* __restrict__ rowptr, int* __restrict__ cursor)
{
    __shared__ int ts[256];
    __shared__ int chunkbase;
    const int b = blockIdx.x, t = threadIdx.x;
    if (t == 0){
        int acc = 0;
        for (int c = 0; c < b; c++) acc += csum[c];
        chunkbase = acc;
    }
    const int base = b * SCHSZ;
    const int lim = min(base + SCHSZ, N_NODES);
    const int idx0 = base + t * 4;          // 4 nodes/thread (256*4 = 1024 >= 782)
    int c[4];
    int local = 0;
    #pragma unroll
    for (int j = 0; j < 4; j++){
        int idx = idx0 + j;
        c[j] = (idx < lim) ? cnt[idx] : 0;
        local += c[j];
    }
    ts[t] = local;
    __syncthreads();
    for (int off = 1; off < 256; off <<= 1){
        int v = (t >= off) ? ts[t - off] : 0;
        __syncthreads();
        ts[t] += v;
        __syncthreads();
    }
    int off0 = chunkbase + ((t == 0) ? 0 : ts[t - 1]);
    #pragma unroll
    for (int j = 0; j < 4; j++){
        int idx = idx0 + j;
        if (idx < lim){
            rowptr[idx] = off0;
            cursor[idx] = off0;
            off0 += c[j];
        }
    }
    if (b == SCH - 1 && t == 255) rowptr[N_NODES] = chunkbase + ts[255];
}

// edge scatter; blocks 0..63 additionally scatter their node-chunk into norder
// using block-local LDS cursors seeded from chist (distributed counting-sort).
// ASCENDING degree order (verified R9/R10; R12's descending failed replay check).
__global__ __launch_bounds__(256) void scatter_kernel(
    const int* __restrict__ src, const int* __restrict__ dst,
    int* __restrict__ cursor, int2* __restrict__ es, int n_edges,
    const int* __restrict__ cnt, const int* __restrict__ chist, int* __restrict__ norder)
{
    __shared__ int chs[SCH * 64];   // 16 KB
    __shared__ int bt[64];
    __shared__ int bb[64];
    __shared__ int cur[64];
    const int b = blockIdx.x, t = threadIdx.x;
    const bool sorter = (b < SCH);
    int pre = 0;
    if (sorter){
        for (int i = t; i < SCH * 64; i += 256) chs[i] = chist[i];
        __syncthreads();
        if (t < 64){
            int tot = 0;
            for (int c = 0; c < SCH; c++){
                int v = chs[c * 64 + t];
                tot += v;
                if (c < b) pre += v;
            }
            bt[t] = tot;
        }
        __syncthreads();
        if (t == 0){
            int a = 0;
            for (int d = 0; d < 64; d++){ int v = bt[d]; bb[d] = a; a += v; }
        }
        __syncthreads();
        if (t < 64) cur[t] = bb[t] + pre;
        __syncthreads();
    }
    int e = b * 256 + t;
    if (e < n_edges){
        int d = dst[e];
        int pos = atomicAdd(&cursor[d], 1);
        es[pos] = make_int2(e, src[e]);
    }
    if (sorter){
        const int base = b * SCHSZ;
        const int lim = min(base + SCHSZ, N_NODES);
        for (int i = base + t; i < lim; i += 256){
            int d = cnt[i]; if (d > 63) d = 63;
            int pos = atomicAdd(&cur[d], 1);
            norder[pos] = i;
        }
    }
}

// ============== fused tail: permute_attr + x->bf16 + pack 3 layers (+Wqe fold, qwb) ==============
__device__ __forceinline__ void pack_item(const float* __restrict__ Wq, const float* __restrict__ Wk,
                                          const float* __restrict__ Wv, const float* __restrict__ Ws,
                                          const float* __restrict__ We, ushort_t* __restrict__ Bp,
                                          int K, int item){
    int n = item % 640, k = item / 640;
    float val;
    if (n < 512){
        const float* W = (n < 128) ? Wq : (n < 256) ? Wk : (n < 384) ? Wv : Ws;
        val = W[k * HC + (n & 127)];
    } else {
        int col = n - 512, h5 = (col >> 5) * 32, d = col & 31;
        float acc = 0.f;
        for (int c = 0; c < 32; c++)
            acc = fmaf(Wq[k * HC + h5 + c], We[d * HC + h5 + c], acc);
        val = acc;
    }
    Bp[(((size_t)(k >> 3)) * 640 + n) * 8 + (k & 7)] = f2bf(val);
}

#define T_S0 12800000            // permute_attr items (E*16)
#define T_S1 16000000            // + convert items (N*256/4)
#define T_S2 16163840            // + pack L0 (256*640)
#define T_S3 16245760            // + pack L1 (128*640)
#define T_S4 16327680            // + pack L2 (128*640)
#define T_S5 16328064            // + qwb (3*128)

__global__ __launch_bounds__(256) void tail_kernel(
    const float* __restrict__ attr, const int2* __restrict__ es,
    const float* __restrict__ x, int perm_mode,
    ushort_t* __restrict__ attr_bf, ushort_t* __restrict__ Xbf,
    const float* __restrict__ Wq0, const float* __restrict__ bq0, const float* __restrict__ Wk0,
    const float* __restrict__ Wv0, const float* __restrict__ Ws0, const float* __restrict__ We0,
    const float* __restrict__ Wq1, const float* __restrict__ bq1, const float* __restrict__ Wk1,
    const float* __restrict__ Wv1, const float* __restrict__ Ws1, const float* __restrict__ We1,
    const float* __restrict__ Wq2, const float* __restrict__ bq2, const float* __restrict__ Wk2,
    const float* __restrict__ Wv2, const float* __restrict__ Ws2, const float* __restrict__ We2,
    ushort_t* __restrict__ Bp0, ushort_t* __restrict__ Bp1, ushort_t* __restrict__ Bp2,
    float* __restrict__ qwb3)
{
    const int stride = gridDim.x * blockDim.x;
    for (int gi = blockIdx.x * blockDim.x + threadIdx.x; gi < T_S5; gi += stride){
        if (gi < T_S0){
            if (perm_mode){
                int grp = gi >> 4, lane = gi & 15;
                int e = es[grp].x;
                const float2 v = *(const float2*)&attr[(size_t)e * ED + lane * 2];
                unsigned r = (unsigned)f2bf(v.x) | ((unsigned)f2bf(v.y) << 16);
                ((unsigned*)attr_bf)[(size_t)grp * (ED / 2) + lane] = r;
            }
        } else if (gi < T_S1){
            int i = gi - T_S0;
            float4 v = ((const float4*)x)[i];
            ushort_t r0 = f2bf(v.x), r1 = f2bf(v.y), r2 = f2bf(v.z), r3 = f2bf(v.w);
            ((ushort4*)Xbf)[i] = make_ushort4(r0, r1, r2, r3);
        } else if (gi < T_S2){
            pack_item(Wq0, Wk0, Wv0, Ws0, We0, Bp0, 256, gi - T_S1);
        } else if (gi < T_S3){
            pack_item(Wq1, Wk1, Wv1, Ws1, We1, Bp1, 128, gi - T_S2);
        } else if (gi < T_S4){
            pack_item(Wq2, Wk2, Wv2, Ws2, We2, Bp2, 128, gi - T_S3);
        } else {
            int f = gi - T_S4;
            int l = f >> 7, t2 = f & 127;
            const float* bq = (l == 0) ? bq0 : (l == 1) ? bq1 : bq2;
            const float* We = (l == 0) ? We0 : (l == 1) ? We1 : We2;
            int h5 = (t2 >> 5) * 32, d = t2 & 31;
            float acc = 0.f;
            for (int c = 0; c < 32; c++)
                acc = fmaf(bq[h5 + c], We[d * HC + h5 + c], acc);
            qwb3[l * HC + t2] = acc;
        }
    }
}

// ===================== MFMA GEMM: [M,K]bf16 @ [K,640]bf16 + bias ====
template<int K>
__global__ __launch_bounds__(320) void gemm_mfma(
    const ushort_t* __restrict__ Xbf, const ushort_t* __restrict__ Bpack,
    const float* __restrict__ b0, const float* __restrict__ b1,
    const float* __restrict__ b2, const float* __restrict__ b3,
    const float* __restrict__ b4,
    float* __restrict__ Yq, ushort_t* __restrict__ Ykbf,
    ushort_t* __restrict__ Yvbf, float* __restrict__ Ys,
    float* __restrict__ Yw, int M)
{
    const int w = threadIdx.x >> 6;
    const int lane = threadIdx.x & 63;
    const int q = lane >> 4, nn = lane & 15;
    const int row0 = blockIdx.x * 32;

    f32x4 acc[2][8];
    #pragma unroll
    for (int mt = 0; mt < 2; mt++)
        #pragma unroll
        for (int nt = 0; nt < 8; nt++)
            acc[mt][nt] = (f32x4){0.f, 0.f, 0.f, 0.f};

    const int r0 = row0 + nn;
    const int r1 = row0 + 16 + nn;
    const bf16x8 zf = (bf16x8){0,0,0,0,0,0,0,0};

    #pragma unroll
    for (int kc = 0; kc < K / 32; kc++){
        bf16x8 a0 = (r0 < M) ? *(const bf16x8*)&Xbf[(size_t)r0 * K + kc * 32 + q * 8] : zf;
        bf16x8 a1 = (r1 < M) ? *(const bf16x8*)&Xbf[(size_t)r1 * K + kc * 32 + q * 8] : zf;
        bf16x8 b[8];
        #pragma unroll
        for (int nt = 0; nt < 8; nt++){
            int n = w * 128 + nt * 16 + nn;
            b[nt] = *(const bf16x8*)&Bpack[(((size_t)(kc * 4 + q)) * 640 + n) * 8];
        }
        #pragma unroll
        for (int nt = 0; nt < 8; nt++){
            acc[0][nt] = __builtin_amdgcn_mfma_f32_16x16x32_bf16(a0, b[nt], acc[0][nt], 0, 0, 0);
            acc[1][nt] = __builtin_amdgcn_mfma_f32_16x16x32_bf16(a1, b[nt], acc[1][nt], 0, 0, 0);
        }
    }

    const float scale = (w == 0 || w == 4) ? 0.17677669529663687f : 1.f;
    const float* bias = (w == 0) ? b0 : (w == 1) ? b1 : (w == 2) ? b2 : (w == 3) ? b3 : b4;

    if (w == 1 || w == 2){
        ushort_t* Yb = (w == 1) ? Ykbf : Yvbf;
        #pragma unroll
        for (int nt = 0; nt < 8; nt++){
            int col = nt * 16 + nn;
            float bval = bias[col];
            #pragma unroll
            for (int mt = 0; mt < 2; mt++){
                #pragma unroll
                for (int r = 0; r < 4; r++){
                    int row = row0 + mt * 16 + q * 4 + r;
                    if (row < M) Yb[(size_t)row * HC + col] = f2bf(acc[mt][nt][r] + bval);
                }
            }
        }
    } else {
        float* Y = (w == 0) ? Yq : (w == 3) ? Ys : Yw;
        #pragma unroll
        for (int nt = 0; nt < 8; nt++){
            int col = nt * 16 + nn;
            float bval = bias[col];
            #pragma unroll
            for (int mt = 0; mt < 2; mt++){
                #pragma unroll
                for (int r = 0; r < 4; r++){
                    int row = row0 + mt * 16 + q * 4 + r;
                    if (row < M) Y[(size_t)row * HC + col] = (acc[mt][nt][r] + bval) * scale;
                }
            }
        }
    }
}

// ===================== fused per-node attention (R10-verified + setprio) =====================
__device__ __forceinline__ float dot16s(const uint4 kk, const uint4 aa,
                                        const float4 qA, const float4 qB,
                                        const float4 wA, const float4 wB){
    float pa =            bflo(kk.x) * qA.x;
    pa = fmaf(bfhi(kk.x), qA.y, pa);
    pa = fmaf(bflo(kk.y), qA.z, pa);
    pa = fmaf(bfhi(kk.y), qA.w, pa);
    pa = fmaf(bflo(aa.x), wA.x, pa);
    pa = fmaf(bfhi(aa.x), wA.y, pa);
    pa = fmaf(bflo(aa.y), wA.z, pa);
    pa = fmaf(bfhi(aa.y), wA.w, pa);
    float pb =            bflo(kk.z) * qB.x;
    pb = fmaf(bfhi(kk.z), qB.y, pb);
    pb = fmaf(bflo(kk.w), qB.z, pb);
    pb = fmaf(bfhi(kk.w), qB.w, pb);
    pb = fmaf(bflo(aa.z), wB.x, pb);
    pb = fmaf(bfhi(aa.z), wB.y, pb);
    pb = fmaf(bflo(aa.w), wB.z, pb);
    pb = fmaf(bfhi(aa.w), wB.w, pb);
    return pa + pb;
}

__device__ __forceinline__ uint4 packrow(const float* p){
    float4 x = *(const float4*)p;
    float4 y = *(const float4*)(p + 4);
    uint4 r;
    r.x = (unsigned)f2bf(x.x) | ((unsigned)f2bf(x.y) << 16);
    r.y = (unsigned)f2bf(x.z) | ((unsigned)f2bf(x.w) << 16);
    r.z = (unsigned)f2bf(y.x) | ((unsigned)f2bf(y.y) << 16);
    r.w = (unsigned)f2bf(y.z) | ((unsigned)f2bf(y.w) << 16);
    return r;
}

__global__ __launch_bounds__(256) void fused_attn_kernel(
    const float* __restrict__ qs, const float* __restrict__ qw,
    const ushort_t* __restrict__ kb, const ushort_t* __restrict__ vb,
    const float* __restrict__ skip, const float* __restrict__ We,
    const float* __restrict__ attr, const ushort_t* __restrict__ attr_bf, int perm_mode,
    const int* __restrict__ rowptr, const int2* __restrict__ es,
    const int* __restrict__ norder,
    float* __restrict__ acsr, float* __restrict__ a_out,
    const float* __restrict__ g, const float* __restrict__ be,
    float* __restrict__ out_f32, ushort_t* __restrict__ out_bf, int apply_ln)
{
    __shared__ float WeT[5120];         // 128 rows x stride 40 (bijective quad-rotated) f32
    __shared__ float SL[2304];          // 16 nodes x 144
    const int t = threadIdx.x;
    for (int idx = t; idx < ED * HC; idx += 256){
        int d = idx >> 7, c = idx & 127;
        WeT[weidx(c, d)] = We[idx];
    }
    __syncthreads();

    const int lane = t & 63, wvi = t >> 6;
    const int qq = lane >> 4, li = lane & 15;
    const int h = li >> 2, jj = li & 3;
    const int gq = blockIdx.x * 16 + wvi * 4 + qq;
    if (gq >= N_NODES) return;
    const int n = norder[gq];
    const int ch = h * 32 + jj * 8;
    const size_t nrow = (size_t)n * HC + ch;

    const float4 qA = *(const float4*)&qs[nrow];
    const float4 qB = *(const float4*)&qs[nrow + 4];
    const float4 wA = *(const float4*)&qw[nrow];
    const float4 wB = *(const float4*)&qw[nrow + 4];
    const float4 skA = *(const float4*)&skip[nrow];
    const float4 skB = *(const float4*)&skip[nrow + 4];

    const int beg = rowptr[n], end = rowptr[n + 1];
    float m = -1e30f, s = 0.f;
    float acc[8] = {0,0,0,0,0,0,0,0};
    float S[8]   = {0,0,0,0,0,0,0,0};

    __builtin_amdgcn_s_setprio(1);      // independent waves: favor the compute wave (m191)
    for (int i = beg; i < end; i += 4){
        const int cnt = end - i;
        uint4 kk[4], vv[4], aa[4];
        #pragma unroll
        for (int b = 0; b < 4; b++){
            kk[b] = (uint4){0,0,0,0}; vv[b] = (uint4){0,0,0,0}; aa[b] = (uint4){0,0,0,0};
            if (b < cnt){
                const int2 e = es[i + b];
                kk[b] = *(const uint4*)&kb[(size_t)e.y * HC + ch];
                vv[b] = *(const uint4*)&vb[(size_t)e.y * HC + ch];
                if (perm_mode)
                    aa[b] = *(const uint4*)&attr_bf[(size_t)(i + b) * ED + jj * 8];
                else
                    aa[b] = packrow(&attr[(size_t)e.x * ED + jj * 8]);
            }
        }
        float al[4];
        #pragma unroll
        for (int b = 0; b < 4; b++){
            float p = dot16s(kk[b], aa[b], qA, qB, wA, wB);
            p += __shfl_xor(p, 1);
            p += __shfl_xor(p, 2);
            al[b] = (b < cnt) ? p : -1e38f;
        }
        if (jj == 0){
            #pragma unroll
            for (int b = 0; b < 4; b++)
                if (b < cnt) acsr[(size_t)(i + b) * 4 + h] = al[b];
        }
        const float mn = fmaxf(fmaxf(m, fmaxf(al[0], al[1])), fmaxf(al[2], al[3]));
        const float sc = __expf(m - mn);
        m = mn;
        const float w0 = __expf(al[0] - mn);
        const float w1 = __expf(al[1] - mn);
        const float w2 = __expf(al[2] - mn);
        const float w3 = __expf(al[3] - mn);
        s = fmaf(s, sc, (w0 + w1) + (w2 + w3));
        acc[0] = fmaf(acc[0], sc, fmaf(w0, bflo(vv[0].x), fmaf(w1, bflo(vv[1].x), fmaf(w2, bflo(vv[2].x), w3 * bflo(vv[3].x)))));
        acc[1] = fmaf(acc[1], sc, fmaf(w0, bfhi(vv[0].x), fmaf(w1, bfhi(vv[1].x), fmaf(w2, bfhi(vv[2].x), w3 * bfhi(vv[3].x)))));
        acc[2] = fmaf(acc[2], sc, fmaf(w0, bflo(vv[0].y), fmaf(w1, bflo(vv[1].y), fmaf(w2, bflo(vv[2].y), w3 * bflo(vv[3].y)))));
        acc[3] = fmaf(acc[3], sc, fmaf(w0, bfhi(vv[0].y), fmaf(w1, bfhi(vv[1].y), fmaf(w2, bfhi(vv[2].y), w3 * bfhi(vv[3].y)))));
        acc[4] = fmaf(acc[4], sc, fmaf(w0, bflo(vv[0].z), fmaf(w1, bflo(vv[1].z), fmaf(w2, bflo(vv[2].z), w3 * bflo(vv[3].z)))));
        acc[5] = fmaf(acc[5], sc, fmaf(w0, bfhi(vv[0].z), fmaf(w1, bfhi(vv[1].z), fmaf(w2, bfhi(vv[2].z), w3 * bfhi(vv[3].z)))));
        acc[6] = fmaf(acc[6], sc, fmaf(w0, bflo(vv[0].w), fmaf(w1, bflo(vv[1].w), fmaf(w2, bflo(vv[2].w), w3 * bflo(vv[3].w)))));
        acc[7] = fmaf(acc[7], sc, fmaf(w0, bfhi(vv[0].w), fmaf(w1, bfhi(vv[1].w), fmaf(w2, bfhi(vv[2].w), w3 * bfhi(vv[3].w)))));
        S[0] = fmaf(S[0], sc, fmaf(w0, bflo(aa[0].x), fmaf(w1, bflo(aa[1].x), fmaf(w2, bflo(aa[2].x), w3 * bflo(aa[3].x)))));
        S[1] = fmaf(S[1], sc, fmaf(w0, bfhi(aa[0].x), fmaf(w1, bfhi(aa[1].x), fmaf(w2, bfhi(aa[2].x), w3 * bfhi(aa[3].x)))));
        S[2] = fmaf(S[2], sc, fmaf(w0, bflo(aa[0].y), fmaf(w1, bflo(aa[1].y), fmaf(w2, bflo(aa[2].y), w3 * bflo(aa[3].y)))));
        S[3] = fmaf(S[3], sc, fmaf(w0, bfhi(aa[0].y), fmaf(w1, bfhi(aa[1].y), fmaf(w2, bfhi(aa[2].y), w3 * bfhi(aa[3].y)))));
        S[4] = fmaf(S[4], sc, fmaf(w0, bflo(aa[0].z), fmaf(w1, bflo(aa[1].z), fmaf(w2, bflo(aa[2].z), w3 * bflo(aa[3].z)))));
        S[5] = fmaf(S[5], sc, fmaf(w0, bfhi(aa[0].z), fmaf(w1, bfhi(aa[1].z), fmaf(w2, bfhi(aa[2].z), w3 * bfhi(aa[3].z)))));
        S[6] = fmaf(S[6], sc, fmaf(w0, bflo(aa[0].w), fmaf(w1, bflo(aa[1].w), fmaf(w2, bflo(aa[2].w), w3 * bflo(aa[3].w)))));
        S[7] = fmaf(S[7], sc, fmaf(w0, bfhi(aa[0].w), fmaf(w1, bfhi(aa[1].w), fmaf(w2, bfhi(aa[2].w), w3 * bfhi(aa[3].w)))));
    }
    __builtin_amdgcn_s_setprio(0);

    // ---- E = We_h^T S_h via per-node LDS transpose ----
    const int nl = wvi * 4 + qq;
    const int sbase = nl * 144;
    const int hsk = h * 36;
    *(float4*)&SL[sbase + hsk + jj * 8]     = make_float4(S[0], S[1], S[2], S[3]);
    *(float4*)&SL[sbase + hsk + jj * 8 + 4] = make_float4(S[4], S[5], S[6], S[7]);
    asm volatile("" ::: "memory");     // in-wave LDS write->read ordering
    float E[8] = {0,0,0,0,0,0,0,0};
    #pragma unroll
    for (int d4 = 0; d4 < 8; d4++){
        const float4 sv = *(const float4*)&SL[sbase + hsk + d4 * 4];
        #pragma unroll
        for (int r = 0; r < 8; r++){
            const float4 wv = *(const float4*)&WeT[weidx(ch + r, d4 * 4)];
            E[r] = fmaf(sv.x, wv.x, fmaf(sv.y, wv.y, fmaf(sv.z, wv.z, fmaf(sv.w, wv.w, E[r]))));
        }
    }

    const float inv = 1.f / (s + 1e-16f);
    float o[8];
    o[0] = (acc[0] + E[0]) * inv + skA.x;
    o[1] = (acc[1] + E[1]) * inv + skA.y;
    o[2] = (acc[2] + E[2]) * inv + skA.z;
    o[3] = (acc[3] + E[3]) * inv + skA.w;
    o[4] = (acc[4] + E[4]) * inv + skB.x;
    o[5] = (acc[5] + E[5]) * inv + skB.y;
    o[6] = (acc[6] + E[6]) * inv + skB.z;
    o[7] = (acc[7] + E[7]) * inv + skB.w;

    if (apply_ln){
        float s1 = 0.f, s2 = 0.f;
        #pragma unroll
        for (int r = 0; r < 8; r++){ s1 += o[r]; s2 = fmaf(o[r], o[r], s2); }
        #pragma unroll
        for (int off = 1; off <= 8; off <<= 1){
            s1 += __shfl_xor(s1, off);
            s2 += __shfl_xor(s2, off);
        }
        const float mu  = s1 * (1.f / 128.f);
        const float var = s2 * (1.f / 128.f) - mu * mu;
        const float ivs = rsqrtf(var + 1e-5f);
        const float4 gA = *(const float4*)&g[ch];
        const float4 gB = *(const float4*)&g[ch + 4];
        const float4 bA = *(const float4*)&be[ch];
        const float4 bB = *(const float4*)&be[ch + 4];
        o[0] = fmaxf((o[0] - mu) * ivs * gA.x + bA.x, 0.f);
        o[1] = fmaxf((o[1] - mu) * ivs * gA.y + bA.y, 0.f);
        o[2] = fmaxf((o[2] - mu) * ivs * gA.z + bA.z, 0.f);
        o[3] = fmaxf((o[3] - mu) * ivs * gA.w + bA.w, 0.f);
        o[4] = fmaxf((o[4] - mu) * ivs * gB.x + bB.x, 0.f);
        o[5] = fmaxf((o[5] - mu) * ivs * gB.y + bB.y, 0.f);
        o[6] = fmaxf((o[6] - mu) * ivs * gB.z + bB.z, 0.f);
        o[7] = fmaxf((o[7] - mu) * ivs * gB.w + bB.w, 0.f);
        uint4 st;
        st.x = (unsigned)f2bf(o[0]) | ((unsigned)f2bf(o[1]) << 16);
        st.y = (unsigned)f2bf(o[2]) | ((unsigned)f2bf(o[3]) << 16);
        st.z = (unsigned)f2bf(o[4]) | ((unsigned)f2bf(o[5]) << 16);
        st.w = (unsigned)f2bf(o[6]) | ((unsigned)f2bf(o[7]) << 16);
        *(uint4*)&out_bf[nrow] = st;
    } else {
        *(float4*)&out_f32[nrow]     = make_float4(o[0], o[1], o[2], o[3]);
        *(float4*)&out_f32[nrow + 4] = make_float4(o[4], o[5], o[6], o[7]);
    }

    // ---- fused norm_a ----
    const float mh = __shfl(m, (qq << 4) + ((li & 3) << 2));
    const float dh = __shfl(s, (qq << 4) + ((li & 3) << 2));
    const float ih = 1.f / (dh + 1e-16f);
    asm volatile("s_waitcnt vmcnt(0)" ::: "memory");   // our acsr stores visible
    for (int f = beg * 4 + li; f < end * 4; f += 16){
        const int e = es[f >> 2].x;
        a_out[(size_t)e * 4 + (li & 3)] = __expf(acsr[f] - mh) * ih;
    }
}

// ============================ launch ============================

extern "C" void kernel_launch(void* const* d_in, const int* in_sizes, int n_in,
                              void* d_out, int out_size, void* d_ws, size_t ws_size,
                              hipStream_t stream) {
    const float* x    = (const float*)d_in[0];
    const int*   ei   = (const int*)  d_in[1];
    const float* attr = (const float*)d_in[2];
    const float* gln[2]  = { (const float*)d_in[30], (const float*)d_in[32] };
    const float* beln[2] = { (const float*)d_in[31], (const float*)d_in[33] };

    float* out   = (float*)d_out;
    float* h_out = out;
    float* a_out[3] = { out + (size_t)N_NODES * HC,
                        out + (size_t)N_NODES * HC + (size_t)E_EDGES * 4,
                        out + (size_t)N_NODES * HC + (size_t)2 * E_EDGES * 4 };

    // ---- workspace layout (64B-aligned chunks); attr_bf LAST (perm-gated) ----
    char* base = (char*)d_ws;
    size_t off = 0;
    auto alloc = [&](size_t bytes) -> void* {
        void* p = base + off;
        off = (off + bytes + 63) & ~(size_t)63;
        return p;
    };
    const size_t NB = (size_t)N_NODES * HC;
    float* qbuf     = (float*)alloc(NB * 4);
    float* qwbuf    = (float*)alloc(NB * 4);
    ushort_t* kbf   = (ushort_t*)alloc(NB * 2);
    ushort_t* vbf   = (ushort_t*)alloc(NB * 2);
    float* sbuf     = (float*)alloc(NB * 4);
    int* rowptr     = (int*)alloc((N_NODES + 1) * 4);
    int* cnt        = (int*)alloc(N_NODES * 4);
    int* cursor     = (int*)alloc(N_NODES * 4);
    int* norder     = (int*)alloc(N_NODES * 4);
    int* chist      = (int*)alloc(SCH * 64 * 4);
    int* csum       = (int*)alloc(SCH * 4);
    int2* es        = (int2*)alloc((size_t)E_EDGES * 8);
    ushort_t* Xbf   = (ushort_t*)alloc((size_t)N_NODES * 256 * 2);
    ushort_t* Hbf   = (ushort_t*)alloc(NB * 2);
    ushort_t* Bp0   = (ushort_t*)alloc((size_t)256 * 640 * 2);
    ushort_t* Bp1   = (ushort_t*)alloc((size_t)128 * 640 * 2);
    ushort_t* Bp2   = (ushort_t*)alloc((size_t)128 * 640 * 2);
    float* acsr     = (float*)alloc((size_t)E_EDGES * 4 * 4);
    float* qwb3     = (float*)alloc((size_t)3 * HC * 4);
    ushort_t* attr_bf = (ushort_t*)alloc((size_t)E_EDGES * ED * 2);
    const int perm_mode = (ws_size >= off) ? 1 : 0;

    const int* srcp = ei;
    const int* dstp = ei + E_EDGES;

    // ---- prep: 1 memset + 5 kernels (distributed CSR build + counting sort) ----
    hipMemsetAsync(cnt, 0, (size_t)N_NODES * 4, stream);
    hist_kernel<<<(E_EDGES + 255) / 256, 256, 0, stream>>>(dstp, cnt, E_EDGES);
    chunk_hist_kernel<<<SCH, 256, 0, stream>>>(cnt, chist, csum);
    fill_rowptr_kernel<<<SCH, 256, 0, stream>>>(cnt, csum, rowptr, cursor);
    scatter_kernel<<<(E_EDGES + 255) / 256, 256, 0, stream>>>(
        srcp, dstp, cursor, es, E_EDGES, cnt, chist, norder);
    tail_kernel<<<4096, 256, 0, stream>>>(
        attr, es, x, perm_mode, attr_bf, Xbf,
        (const float*)d_in[3],  (const float*)d_in[4],  (const float*)d_in[5],
        (const float*)d_in[7],  (const float*)d_in[10], (const float*)d_in[9],
        (const float*)d_in[12], (const float*)d_in[13], (const float*)d_in[14],
        (const float*)d_in[16], (const float*)d_in[19], (const float*)d_in[18],
        (const float*)d_in[21], (const float*)d_in[22], (const float*)d_in[23],
        (const float*)d_in[25], (const float*)d_in[28], (const float*)d_in[27],
        Bp0, Bp1, Bp2, qwb3);

    const int gemm_grid = (N_NODES + 31) / 32;
    const int attn_grid = (N_NODES + 15) / 16;
    ushort_t* Bps[3] = { Bp0, Bp1, Bp2 };

    for (int l = 0; l < 3; l++){
        const float* bq = (const float*)d_in[3 + 9 * l + 1];
        const float* bk = (const float*)d_in[3 + 9 * l + 3];
        const float* bv = (const float*)d_in[3 + 9 * l + 5];
        const float* We = (const float*)d_in[3 + 9 * l + 6];
        const float* bs = (const float*)d_in[3 + 9 * l + 8];

        if (l == 0)
            gemm_mfma<256><<<gemm_grid, 320, 0, stream>>>(Xbf, Bps[l], bq, bk, bv, bs, qwb3 + 128 * l,
                                                          qbuf, kbf, vbf, sbuf, qwbuf, N_NODES);
        else
            gemm_mfma<128><<<gemm_grid, 320, 0, stream>>>(Hbf, Bps[l], bq, bk, bv, bs, qwb3 + 128 * l,
                                                          qbuf, kbf, vbf, sbuf, qwbuf, N_NODES);

        const float* gg = (l < 2) ? gln[l] : nullptr;
        const float* bb = (l < 2) ? beln[l] : nullptr;
        fused_attn_kernel<<<attn_grid, 256, 0, stream>>>(
            qbuf, qwbuf, kbf, vbf, sbuf, We, attr, attr_bf, perm_mode,
            rowptr, es, norder, acsr, a_out[l], gg, bb,
            (l < 2) ? nullptr : h_out, (l < 2) ? Hbf : nullptr, (l < 2) ? 1 : 0);
    }
}

// Round 14
// 918.123 us; speedup vs baseline: 1.4413x; 1.0218x over previous
//
#include <hip/hip_runtime.h>
#include <math.h>

#define N_NODES 50000
#define E_EDGES 800000
#define HC 128
#define ED 32
#define SCH 64           // sort/scan chunks (one block each)
#define SCHSZ 782        // ceil(N_NODES / SCH); 64*782 = 50048 >= 50000

typedef __attribute__((ext_vector_type(8))) short bf16x8;
typedef __attribute__((ext_vector_type(4))) float f32x4;
typedef unsigned short ushort_t;

__device__ __forceinline__ ushort_t f2bf(float f){
    unsigned u = __float_as_uint(f);
    return (ushort_t)((u + 0x7FFFu + ((u >> 16) & 1u)) >> 16);   // RNE
}
__device__ __forceinline__ float bflo(unsigned u){ return __uint_as_float(u << 16); }
__device__ __forceinline__ float bfhi(unsigned u){ return __uint_as_float(u & 0xffff0000u); }

// WeT layout: stride 40, per-row quad-rotation. BIJECTIVE, float4-aligned,
// read bank-quad spread -> <=2-way (free). Verified correct in R4.
__device__ __forceinline__ int weidx(int c, int d){
    return c * 40 + (((((d >> 2) + ((c >> 3) & 7)) & 7)) << 2) + (d & 3);
}

// ============================ CSR build ============================
// R11: cooperative grid.sync() @1024 blocks ~100us each -> 5 small dispatches win.
// R12: descending (LPT) norder failed the replay-divergence tripwire.
// R13: s_setprio(1) in attn was neutral-to-negative (no wave role diversity).
// This is the R10-verified configuration (best measured: 925us).

__global__ void hist_kernel(const int* __restrict__ dst, int* __restrict__ cnt, int n_edges){
    int e = blockIdx.x * blockDim.x + threadIdx.x;
    if (e < n_edges) atomicAdd(&cnt[dst[e]], 1);
}

// per-chunk degree histogram + per-chunk edge total (64 blocks).
__global__ __launch_bounds__(256) void chunk_hist_kernel(const int* __restrict__ cnt,
                                                         int* __restrict__ chist,
                                                         int* __restrict__ csum){
    __shared__ int hist[64];
    __shared__ int red[256];
    const int t = threadIdx.x, b = blockIdx.x;
    if (t < 64) hist[t] = 0;
    __syncthreads();
    const int base = b * SCHSZ;
    const int lim = min(base + SCHSZ, N_NODES);
    int mysum = 0;
    for (int i = base + t; i < lim; i += 256){
        int d = cnt[i];
        mysum += d;
        if (d > 63) d = 63;
        atomicAdd(&hist[d], 1);
    }
    red[t] = mysum;
    __syncthreads();
    for (int off = 128; off; off >>= 1){
        if (t < off) red[t] += red[t + off];
        __syncthreads();
    }
    if (t < 64) chist[b * 64 + t] = hist[t];
    if (t == 0) csum[b] = red[0];
}

// 64 blocks: each block prefixes csum for its chunk base, then block-scans its
// 782 node degrees -> rowptr/cursor.
__global__ __launch_bounds__(256) void fill_rowptr_kernel(
    const int* __restrict__ cnt, const int* __restrict__ csum,
    int* __restrict__ rowptr, int* __restrict__ cursor)
{
    __shared__ int ts[256];
    __shared__ int chunkbase;
    const int b = blockIdx.x, t = threadIdx.x;
    if (t == 0){
        int acc = 0;
        for (int c = 0; c < b; c++) acc += csum[c];
        chunkbase = acc;
    }
    const int base = b * SCHSZ;
    const int lim = min(base + SCHSZ, N_NODES);
    const int idx0 = base + t * 4;          // 4 nodes/thread (256*4 = 1024 >= 782)
    int c[4];
    int local = 0;
    #pragma unroll
    for (int j = 0; j < 4; j++){
        int idx = idx0 + j;
        c[j] = (idx < lim) ? cnt[idx] : 0;
        local += c[j];
    }
    ts[t] = local;
    __syncthreads();
    for (int off = 1; off < 256; off <<= 1){
        int v = (t >= off) ? ts[t - off] : 0;
        __syncthreads();
        ts[t] += v;
        __syncthreads();
    }
    int off0 = chunkbase + ((t == 0) ? 0 : ts[t - 1]);
    #pragma unroll
    for (int j = 0; j < 4; j++){
        int idx = idx0 + j;
        if (idx < lim){
            rowptr[idx] = off0;
            cursor[idx] = off0;
            off0 += c[j];
        }
    }
    if (b == SCH - 1 && t == 255) rowptr[N_NODES] = chunkbase + ts[255];
}

// edge scatter; blocks 0..63 additionally scatter their node-chunk into norder
// using block-local LDS cursors seeded from chist (distributed counting-sort).
// ASCENDING degree order (verified R9/R10).
__global__ __launch_bounds__(256) void scatter_kernel(
    const int* __restrict__ src, const int* __restrict__ dst,
    int* __restrict__ cursor, int2* __restrict__ es, int n_edges,
    const int* __restrict__ cnt, const int* __restrict__ chist, int* __restrict__ norder)
{
    __shared__ int chs[SCH * 64];   // 16 KB
    __shared__ int bt[64];
    __shared__ int bb[64];
    __shared__ int cur[64];
    const int b = blockIdx.x, t = threadIdx.x;
    const bool sorter = (b < SCH);
    int pre = 0;
    if (sorter){
        for (int i = t; i < SCH * 64; i += 256) chs[i] = chist[i];
        __syncthreads();
        if (t < 64){
            int tot = 0;
            for (int c = 0; c < SCH; c++){
                int v = chs[c * 64 + t];
                tot += v;
                if (c < b) pre += v;
            }
            bt[t] = tot;
        }
        __syncthreads();
        if (t == 0){
            int a = 0;
            for (int d = 0; d < 64; d++){ int v = bt[d]; bb[d] = a; a += v; }
        }
        __syncthreads();
        if (t < 64) cur[t] = bb[t] + pre;
        __syncthreads();
    }
    int e = b * 256 + t;
    if (e < n_edges){
        int d = dst[e];
        int pos = atomicAdd(&cursor[d], 1);
        es[pos] = make_int2(e, src[e]);
    }
    if (sorter){
        const int base = b * SCHSZ;
        const int lim = min(base + SCHSZ, N_NODES);
        for (int i = base + t; i < lim; i += 256){
            int d = cnt[i]; if (d > 63) d = 63;
            int pos = atomicAdd(&cur[d], 1);
            norder[pos] = i;
        }
    }
}

// ============== fused tail: permute_attr + x->bf16 + pack 3 layers (+Wqe fold, qwb) ==============
__device__ __forceinline__ void pack_item(const float* __restrict__ Wq, const float* __restrict__ Wk,
                                          const float* __restrict__ Wv, const float* __restrict__ Ws,
                                          const float* __restrict__ We, ushort_t* __restrict__ Bp,
                                          int K, int item){
    int n = item % 640, k = item / 640;
    float val;
    if (n < 512){
        const float* W = (n < 128) ? Wq : (n < 256) ? Wk : (n < 384) ? Wv : Ws;
        val = W[k * HC + (n & 127)];
    } else {
        int col = n - 512, h5 = (col >> 5) * 32, d = col & 31;
        float acc = 0.f;
        for (int c = 0; c < 32; c++)
            acc = fmaf(Wq[k * HC + h5 + c], We[d * HC + h5 + c], acc);
        val = acc;
    }
    Bp[(((size_t)(k >> 3)) * 640 + n) * 8 + (k & 7)] = f2bf(val);
}

#define T_S0 12800000            // permute_attr items (E*16)
#define T_S1 16000000            // + convert items (N*256/4)
#define T_S2 16163840            // + pack L0 (256*640)
#define T_S3 16245760            // + pack L1 (128*640)
#define T_S4 16327680            // + pack L2 (128*640)
#define T_S5 16328064            // + qwb (3*128)

__global__ __launch_bounds__(256) void tail_kernel(
    const float* __restrict__ attr, const int2* __restrict__ es,
    const float* __restrict__ x, int perm_mode,
    ushort_t* __restrict__ attr_bf, ushort_t* __restrict__ Xbf,
    const float* __restrict__ Wq0, const float* __restrict__ bq0, const float* __restrict__ Wk0,
    const float* __restrict__ Wv0, const float* __restrict__ Ws0, const float* __restrict__ We0,
    const float* __restrict__ Wq1, const float* __restrict__ bq1, const float* __restrict__ Wk1,
    const float* __restrict__ Wv1, const float* __restrict__ Ws1, const float* __restrict__ We1,
    const float* __restrict__ Wq2, const float* __restrict__ bq2, const float* __restrict__ Wk2,
    const float* __restrict__ Wv2, const float* __restrict__ Ws2, const float* __restrict__ We2,
    ushort_t* __restrict__ Bp0, ushort_t* __restrict__ Bp1, ushort_t* __restrict__ Bp2,
    float* __restrict__ qwb3)
{
    const int stride = gridDim.x * blockDim.x;
    for (int gi = blockIdx.x * blockDim.x + threadIdx.x; gi < T_S5; gi += stride){
        if (gi < T_S0){
            if (perm_mode){
                int grp = gi >> 4, lane = gi & 15;
                int e = es[grp].x;
                const float2 v = *(const float2*)&attr[(size_t)e * ED + lane * 2];
                unsigned r = (unsigned)f2bf(v.x) | ((unsigned)f2bf(v.y) << 16);
                ((unsigned*)attr_bf)[(size_t)grp * (ED / 2) + lane] = r;
            }
        } else if (gi < T_S1){
            int i = gi - T_S0;
            float4 v = ((const float4*)x)[i];
            ushort_t r0 = f2bf(v.x), r1 = f2bf(v.y), r2 = f2bf(v.z), r3 = f2bf(v.w);
            ((ushort4*)Xbf)[i] = make_ushort4(r0, r1, r2, r3);
        } else if (gi < T_S2){
            pack_item(Wq0, Wk0, Wv0, Ws0, We0, Bp0, 256, gi - T_S1);
        } else if (gi < T_S3){
            pack_item(Wq1, Wk1, Wv1, Ws1, We1, Bp1, 128, gi - T_S2);
        } else if (gi < T_S4){
            pack_item(Wq2, Wk2, Wv2, Ws2, We2, Bp2, 128, gi - T_S3);
        } else {
            int f = gi - T_S4;
            int l = f >> 7, t2 = f & 127;
            const float* bq = (l == 0) ? bq0 : (l == 1) ? bq1 : bq2;
            const float* We = (l == 0) ? We0 : (l == 1) ? We1 : We2;
            int h5 = (t2 >> 5) * 32, d = t2 & 31;
            float acc = 0.f;
            for (int c = 0; c < 32; c++)
                acc = fmaf(bq[h5 + c], We[d * HC + h5 + c], acc);
            qwb3[l * HC + t2] = acc;
        }
    }
}

// ===================== MFMA GEMM: [M,K]bf16 @ [K,640]bf16 + bias ====
template<int K>
__global__ __launch_bounds__(320) void gemm_mfma(
    const ushort_t* __restrict__ Xbf, const ushort_t* __restrict__ Bpack,
    const float* __restrict__ b0, const float* __restrict__ b1,
    const float* __restrict__ b2, const float* __restrict__ b3,
    const float* __restrict__ b4,
    float* __restrict__ Yq, ushort_t* __restrict__ Ykbf,
    ushort_t* __restrict__ Yvbf, float* __restrict__ Ys,
    float* __restrict__ Yw, int M)
{
    const int w = threadIdx.x >> 6;
    const int lane = threadIdx.x & 63;
    const int q = lane >> 4, nn = lane & 15;
    const int row0 = blockIdx.x * 32;

    f32x4 acc[2][8];
    #pragma unroll
    for (int mt = 0; mt < 2; mt++)
        #pragma unroll
        for (int nt = 0; nt < 8; nt++)
            acc[mt][nt] = (f32x4){0.f, 0.f, 0.f, 0.f};

    const int r0 = row0 + nn;
    const int r1 = row0 + 16 + nn;
    const bf16x8 zf = (bf16x8){0,0,0,0,0,0,0,0};

    #pragma unroll
    for (int kc = 0; kc < K / 32; kc++){
        bf16x8 a0 = (r0 < M) ? *(const bf16x8*)&Xbf[(size_t)r0 * K + kc * 32 + q * 8] : zf;
        bf16x8 a1 = (r1 < M) ? *(const bf16x8*)&Xbf[(size_t)r1 * K + kc * 32 + q * 8] : zf;
        bf16x8 b[8];
        #pragma unroll
        for (int nt = 0; nt < 8; nt++){
            int n = w * 128 + nt * 16 + nn;
            b[nt] = *(const bf16x8*)&Bpack[(((size_t)(kc * 4 + q)) * 640 + n) * 8];
        }
        #pragma unroll
        for (int nt = 0; nt < 8; nt++){
            acc[0][nt] = __builtin_amdgcn_mfma_f32_16x16x32_bf16(a0, b[nt], acc[0][nt], 0, 0, 0);
            acc[1][nt] = __builtin_amdgcn_mfma_f32_16x16x32_bf16(a1, b[nt], acc[1][nt], 0, 0, 0);
        }
    }

    const float scale = (w == 0 || w == 4) ? 0.17677669529663687f : 1.f;
    const float* bias = (w == 0) ? b0 : (w == 1) ? b1 : (w == 2) ? b2 : (w == 3) ? b3 : b4;

    if (w == 1 || w == 2){
        ushort_t* Yb = (w == 1) ? Ykbf : Yvbf;
        #pragma unroll
        for (int nt = 0; nt < 8; nt++){
            int col = nt * 16 + nn;
            float bval = bias[col];
            #pragma unroll
            for (int mt = 0; mt < 2; mt++){
                #pragma unroll
                for (int r = 0; r < 4; r++){
                    int row = row0 + mt * 16 + q * 4 + r;
                    if (row < M) Yb[(size_t)row * HC + col] = f2bf(acc[mt][nt][r] + bval);
                }
            }
        }
    } else {
        float* Y = (w == 0) ? Yq : (w == 3) ? Ys : Yw;
        #pragma unroll
        for (int nt = 0; nt < 8; nt++){
            int col = nt * 16 + nn;
            float bval = bias[col];
            #pragma unroll
            for (int mt = 0; mt < 2; mt++){
                #pragma unroll
                for (int r = 0; r < 4; r++){
                    int row = row0 + mt * 16 + q * 4 + r;
                    if (row < M) Y[(size_t)row * HC + col] = (acc[mt][nt][r] + bval) * scale;
                }
            }
        }
    }
}

// ===================== fused per-node attention (R10-verified) =====================
__device__ __forceinline__ float dot16s(const uint4 kk, const uint4 aa,
                                        const float4 qA, const float4 qB,
                                        const float4 wA, const float4 wB){
    float pa =            bflo(kk.x) * qA.x;
    pa = fmaf(bfhi(kk.x), qA.y, pa);
    pa = fmaf(bflo(kk.y), qA.z, pa);
    pa = fmaf(bfhi(kk.y), qA.w, pa);
    pa = fmaf(bflo(aa.x), wA.x, pa);
    pa = fmaf(bfhi(aa.x), wA.y, pa);
    pa = fmaf(bflo(aa.y), wA.z, pa);
    pa = fmaf(bfhi(aa.y), wA.w, pa);
    float pb =            bflo(kk.z) * qB.x;
    pb = fmaf(bfhi(kk.z), qB.y, pb);
    pb = fmaf(bflo(kk.w), qB.z, pb);
    pb = fmaf(bfhi(kk.w), qB.w, pb);
    pb = fmaf(bflo(aa.z), wB.x, pb);
    pb = fmaf(bfhi(aa.z), wB.y, pb);
    pb = fmaf(bflo(aa.w), wB.z, pb);
    pb = fmaf(bfhi(aa.w), wB.w, pb);
    return pa + pb;
}

__device__ __forceinline__ uint4 packrow(const float* p){
    float4 x = *(const float4*)p;
    float4 y = *(const float4*)(p + 4);
    uint4 r;
    r.x = (unsigned)f2bf(x.x) | ((unsigned)f2bf(x.y) << 16);
    r.y = (unsigned)f2bf(x.z) | ((unsigned)f2bf(x.w) << 16);
    r.z = (unsigned)f2bf(y.x) | ((unsigned)f2bf(y.y) << 16);
    r.w = (unsigned)f2bf(y.z) | ((unsigned)f2bf(y.w) << 16);
    return r;
}

__global__ __launch_bounds__(256) void fused_attn_kernel(
    const float* __restrict__ qs, const float* __restrict__ qw,
    const ushort_t* __restrict__ kb, const ushort_t* __restrict__ vb,
    const float* __restrict__ skip, const float* __restrict__ We,
    const float* __restrict__ attr, const ushort_t* __restrict__ attr_bf, int perm_mode,
    const int* __restrict__ rowptr, const int2* __restrict__ es,
    const int* __restrict__ norder,
    float* __restrict__ acsr, float* __restrict__ a_out,
    const float* __restrict__ g, const float* __restrict__ be,
    float* __restrict__ out_f32, ushort_t* __restrict__ out_bf, int apply_ln)
{
    __shared__ float WeT[5120];         // 128 rows x stride 40 (bijective quad-rotated) f32
    __shared__ float SL[2304];          // 16 nodes x 144
    const int t = threadIdx.x;
    for (int idx = t; idx < ED * HC; idx += 256){
        int d = idx >> 7, c = idx & 127;
        WeT[weidx(c, d)] = We[idx];
    }
    __syncthreads();

    const int lane = t & 63, wvi = t >> 6;
    const int qq = lane >> 4, li = lane & 15;
    const int h = li >> 2, jj = li & 3;
    const int gq = blockIdx.x * 16 + wvi * 4 + qq;
    if (gq >= N_NODES) return;
    const int n = norder[gq];
    const int ch = h * 32 + jj * 8;
    const size_t nrow = (size_t)n * HC + ch;

    const float4 qA = *(const float4*)&qs[nrow];
    const float4 qB = *(const float4*)&qs[nrow + 4];
    const float4 wA = *(const float4*)&qw[nrow];
    const float4 wB = *(const float4*)&qw[nrow + 4];
    const float4 skA = *(const float4*)&skip[nrow];
    const float4 skB = *(const float4*)&skip[nrow + 4];

    const int beg = rowptr[n], end = rowptr[n + 1];
    float m = -1e30f, s = 0.f;
    float acc[8] = {0,0,0,0,0,0,0,0};
    float S[8]   = {0,0,0,0,0,0,0,0};

    for (int i = beg; i < end; i += 4){
        const int cnt = end - i;
        uint4 kk[4], vv[4], aa[4];
        #pragma unroll
        for (int b = 0; b < 4; b++){
            kk[b] = (uint4){0,0,0,0}; vv[b] = (uint4){0,0,0,0}; aa[b] = (uint4){0,0,0,0};
            if (b < cnt){
                const int2 e = es[i + b];
                kk[b] = *(const uint4*)&kb[(size_t)e.y * HC + ch];
                vv[b] = *(const uint4*)&vb[(size_t)e.y * HC + ch];
                if (perm_mode)
                    aa[b] = *(const uint4*)&attr_bf[(size_t)(i + b) * ED + jj * 8];
                else
                    aa[b] = packrow(&attr[(size_t)e.x * ED + jj * 8]);
            }
        }
        float al[4];
        #pragma unroll
        for (int b = 0; b < 4; b++){
            float p = dot16s(kk[b], aa[b], qA, qB, wA, wB);
            p += __shfl_xor(p, 1);
            p += __shfl_xor(p, 2);
            al[b] = (b < cnt) ? p : -1e38f;
        }
        if (jj == 0){
            #pragma unroll
            for (int b = 0; b < 4; b++)
                if (b < cnt) acsr[(size_t)(i + b) * 4 + h] = al[b];
        }
        const float mn = fmaxf(fmaxf(m, fmaxf(al[0], al[1])), fmaxf(al[2], al[3]));
        const float sc = __expf(m - mn);
        m = mn;
        const float w0 = __expf(al[0] - mn);
        const float w1 = __expf(al[1] - mn);
        const float w2 = __expf(al[2] - mn);
        const float w3 = __expf(al[3] - mn);
        s = fmaf(s, sc, (w0 + w1) + (w2 + w3));
        acc[0] = fmaf(acc[0], sc, fmaf(w0, bflo(vv[0].x), fmaf(w1, bflo(vv[1].x), fmaf(w2, bflo(vv[2].x), w3 * bflo(vv[3].x)))));
        acc[1] = fmaf(acc[1], sc, fmaf(w0, bfhi(vv[0].x), fmaf(w1, bfhi(vv[1].x), fmaf(w2, bfhi(vv[2].x), w3 * bfhi(vv[3].x)))));
        acc[2] = fmaf(acc[2], sc, fmaf(w0, bflo(vv[0].y), fmaf(w1, bflo(vv[1].y), fmaf(w2, bflo(vv[2].y), w3 * bflo(vv[3].y)))));
        acc[3] = fmaf(acc[3], sc, fmaf(w0, bfhi(vv[0].y), fmaf(w1, bfhi(vv[1].y), fmaf(w2, bfhi(vv[2].y), w3 * bfhi(vv[3].y)))));
        acc[4] = fmaf(acc[4], sc, fmaf(w0, bflo(vv[0].z), fmaf(w1, bflo(vv[1].z), fmaf(w2, bflo(vv[2].z), w3 * bflo(vv[3].z)))));
        acc[5] = fmaf(acc[5], sc, fmaf(w0, bfhi(vv[0].z), fmaf(w1, bfhi(vv[1].z), fmaf(w2, bfhi(vv[2].z), w3 * bfhi(vv[3].z)))));
        acc[6] = fmaf(acc[6], sc, fmaf(w0, bflo(vv[0].w), fmaf(w1, bflo(vv[1].w), fmaf(w2, bflo(vv[2].w), w3 * bflo(vv[3].w)))));
        acc[7] = fmaf(acc[7], sc, fmaf(w0, bfhi(vv[0].w), fmaf(w1, bfhi(vv[1].w), fmaf(w2, bfhi(vv[2].w), w3 * bfhi(vv[3].w)))));
        S[0] = fmaf(S[0], sc, fmaf(w0, bflo(aa[0].x), fmaf(w1, bflo(aa[1].x), fmaf(w2, bflo(aa[2].x), w3 * bflo(aa[3].x)))));
        S[1] = fmaf(S[1], sc, fmaf(w0, bfhi(aa[0].x), fmaf(w1, bfhi(aa[1].x), fmaf(w2, bfhi(aa[2].x), w3 * bfhi(aa[3].x)))));
        S[2] = fmaf(S[2], sc, fmaf(w0, bflo(aa[0].y), fmaf(w1, bflo(aa[1].y), fmaf(w2, bflo(aa[2].y), w3 * bflo(aa[3].y)))));
        S[3] = fmaf(S[3], sc, fmaf(w0, bfhi(aa[0].y), fmaf(w1, bfhi(aa[1].y), fmaf(w2, bfhi(aa[2].y), w3 * bfhi(aa[3].y)))));
        S[4] = fmaf(S[4], sc, fmaf(w0, bflo(aa[0].z), fmaf(w1, bflo(aa[1].z), fmaf(w2, bflo(aa[2].z), w3 * bflo(aa[3].z)))));
        S[5] = fmaf(S[5], sc, fmaf(w0, bfhi(aa[0].z), fmaf(w1, bfhi(aa[1].z), fmaf(w2, bfhi(aa[2].z), w3 * bfhi(aa[3].z)))));
        S[6] = fmaf(S[6], sc, fmaf(w0, bflo(aa[0].w), fmaf(w1, bflo(aa[1].w), fmaf(w2, bflo(aa[2].w), w3 * bflo(aa[3].w)))));
        S[7] = fmaf(S[7], sc, fmaf(w0, bfhi(aa[0].w), fmaf(w1, bfhi(aa[1].w), fmaf(w2, bfhi(aa[2].w), w3 * bfhi(aa[3].w)))));
    }

    // ---- E = We_h^T S_h via per-node LDS transpose ----
    const int nl = wvi * 4 + qq;
    const int sbase = nl * 144;
    const int hsk = h * 36;
    *(float4*)&SL[sbase + hsk + jj * 8]     = make_float4(S[0], S[1], S[2], S[3]);
    *(float4*)&SL[sbase + hsk + jj * 8 + 4] = make_float4(S[4], S[5], S[6], S[7]);
    asm volatile("" ::: "memory");     // in-wave LDS write->read ordering
    float E[8] = {0,0,0,0,0,0,0,0};
    #pragma unroll
    for (int d4 = 0; d4 < 8; d4++){
        const float4 sv = *(const float4*)&SL[sbase + hsk + d4 * 4];
        #pragma unroll
        for (int r = 0; r < 8; r++){
            const float4 wv = *(const float4*)&WeT[weidx(ch + r, d4 * 4)];
            E[r] = fmaf(sv.x, wv.x, fmaf(sv.y, wv.y, fmaf(sv.z, wv.z, fmaf(sv.w, wv.w, E[r]))));
        }
    }

    const float inv = 1.f / (s + 1e-16f);
    float o[8];
    o[0] = (acc[0] + E[0]) * inv + skA.x;
    o[1] = (acc[1] + E[1]) * inv + skA.y;
    o[2] = (acc[2] + E[2]) * inv + skA.z;
    o[3] = (acc[3] + E[3]) * inv + skA.w;
    o[4] = (acc[4] + E[4]) * inv + skB.x;
    o[5] = (acc[5] + E[5]) * inv + skB.y;
    o[6] = (acc[6] + E[6]) * inv + skB.z;
    o[7] = (acc[7] + E[7]) * inv + skB.w;

    if (apply_ln){
        float s1 = 0.f, s2 = 0.f;
        #pragma unroll
        for (int r = 0; r < 8; r++){ s1 += o[r]; s2 = fmaf(o[r], o[r], s2); }
        #pragma unroll
        for (int off = 1; off <= 8; off <<= 1){
            s1 += __shfl_xor(s1, off);
            s2 += __shfl_xor(s2, off);
        }
        const float mu  = s1 * (1.f / 128.f);
        const float var = s2 * (1.f / 128.f) - mu * mu;
        const float ivs = rsqrtf(var + 1e-5f);
        const float4 gA = *(const float4*)&g[ch];
        const float4 gB = *(const float4*)&g[ch + 4];
        const float4 bA = *(const float4*)&be[ch];
        const float4 bB = *(const float4*)&be[ch + 4];
        o[0] = fmaxf((o[0] - mu) * ivs * gA.x + bA.x, 0.f);
        o[1] = fmaxf((o[1] - mu) * ivs * gA.y + bA.y, 0.f);
        o[2] = fmaxf((o[2] - mu) * ivs * gA.z + bA.z, 0.f);
        o[3] = fmaxf((o[3] - mu) * ivs * gA.w + bA.w, 0.f);
        o[4] = fmaxf((o[4] - mu) * ivs * gB.x + bB.x, 0.f);
        o[5] = fmaxf((o[5] - mu) * ivs * gB.y + bB.y, 0.f);
        o[6] = fmaxf((o[6] - mu) * ivs * gB.z + bB.z, 0.f);
        o[7] = fmaxf((o[7] - mu) * ivs * gB.w + bB.w, 0.f);
        uint4 st;
        st.x = (unsigned)f2bf(o[0]) | ((unsigned)f2bf(o[1]) << 16);
        st.y = (unsigned)f2bf(o[2]) | ((unsigned)f2bf(o[3]) << 16);
        st.z = (unsigned)f2bf(o[4]) | ((unsigned)f2bf(o[5]) << 16);
        st.w = (unsigned)f2bf(o[6]) | ((unsigned)f2bf(o[7]) << 16);
        *(uint4*)&out_bf[nrow] = st;
    } else {
        *(float4*)&out_f32[nrow]     = make_float4(o[0], o[1], o[2], o[3]);
        *(float4*)&out_f32[nrow + 4] = make_float4(o[4], o[5], o[6], o[7]);
    }

    // ---- fused norm_a ----
    const float mh = __shfl(m, (qq << 4) + ((li & 3) << 2));
    const float dh = __shfl(s, (qq << 4) + ((li & 3) << 2));
    const float ih = 1.f / (dh + 1e-16f);
    asm volatile("s_waitcnt vmcnt(0)" ::: "memory");   // our acsr stores visible
    for (int f = beg * 4 + li; f < end * 4; f += 16){
        const int e = es[f >> 2].x;
        a_out[(size_t)e * 4 + (li & 3)] = __expf(acsr[f] - mh) * ih;
    }
}

// ============================ launch ============================

extern "C" void kernel_launch(void* const* d_in, const int* in_sizes, int n_in,
                              void* d_out, int out_size, void* d_ws, size_t ws_size,
                              hipStream_t stream) {
    const float* x    = (const float*)d_in[0];
    const int*   ei   = (const int*)  d_in[1];
    const float* attr = (const float*)d_in[2];
    const float* gln[2]  = { (const float*)d_in[30], (const float*)d_in[32] };
    const float* beln[2] = { (const float*)d_in[31], (const float*)d_in[33] };

    float* out   = (float*)d_out;
    float* h_out = out;
    float* a_out[3] = { out + (size_t)N_NODES * HC,
                        out + (size_t)N_NODES * HC + (size_t)E_EDGES * 4,
                        out + (size_t)N_NODES * HC + (size_t)2 * E_EDGES * 4 };

    // ---- workspace layout (64B-aligned chunks); attr_bf LAST (perm-gated) ----
    char* base = (char*)d_ws;
    size_t off = 0;
    auto alloc = [&](size_t bytes) -> void* {
        void* p = base + off;
        off = (off + bytes + 63) & ~(size_t)63;
        return p;
    };
    const size_t NB = (size_t)N_NODES * HC;
    float* qbuf     = (float*)alloc(NB * 4);
    float* qwbuf    = (float*)alloc(NB * 4);
    ushort_t* kbf   = (ushort_t*)alloc(NB * 2);
    ushort_t* vbf   = (ushort_t*)alloc(NB * 2);
    float* sbuf     = (float*)alloc(NB * 4);
    int* rowptr     = (int*)alloc((N_NODES + 1) * 4);
    int* cnt        = (int*)alloc(N_NODES * 4);
    int* cursor     = (int*)alloc(N_NODES * 4);
    int* norder     = (int*)alloc(N_NODES * 4);
    int* chist      = (int*)alloc(SCH * 64 * 4);
    int* csum       = (int*)alloc(SCH * 4);
    int2* es        = (int2*)alloc((size_t)E_EDGES * 8);
    ushort_t* Xbf   = (ushort_t*)alloc((size_t)N_NODES * 256 * 2);
    ushort_t* Hbf   = (ushort_t*)alloc(NB * 2);
    ushort_t* Bp0   = (ushort_t*)alloc((size_t)256 * 640 * 2);
    ushort_t* Bp1   = (ushort_t*)alloc((size_t)128 * 640 * 2);
    ushort_t* Bp2   = (ushort_t*)alloc((size_t)128 * 640 * 2);
    float* acsr     = (float*)alloc((size_t)E_EDGES * 4 * 4);
    float* qwb3     = (float*)alloc((size_t)3 * HC * 4);
    ushort_t* attr_bf = (ushort_t*)alloc((size_t)E_EDGES * ED * 2);
    const int perm_mode = (ws_size >= off) ? 1 : 0;

    const int* srcp = ei;
    const int* dstp = ei + E_EDGES;

    // ---- prep: 1 memset + 5 kernels (distributed CSR build + counting sort) ----
    hipMemsetAsync(cnt, 0, (size_t)N_NODES * 4, stream);
    hist_kernel<<<(E_EDGES + 255) / 256, 256, 0, stream>>>(dstp, cnt, E_EDGES);
    chunk_hist_kernel<<<SCH, 256, 0, stream>>>(cnt, chist, csum);
    fill_rowptr_kernel<<<SCH, 256, 0, stream>>>(cnt, csum, rowptr, cursor);
    scatter_kernel<<<(E_EDGES + 255) / 256, 256, 0, stream>>>(
        srcp, dstp, cursor, es, E_EDGES, cnt, chist, norder);
    tail_kernel<<<4096, 256, 0, stream>>>(
        attr, es, x, perm_mode, attr_bf, Xbf,
        (const float*)d_in[3],  (const float*)d_in[4],  (const float*)d_in[5],
        (const float*)d_in[7],  (const float*)d_in[10], (const float*)d_in[9],
        (const float*)d_in[12], (const float*)d_in[13], (const float*)d_in[14],
        (const float*)d_in[16], (const float*)d_in[19], (const float*)d_in[18],
        (const float*)d_in[21], (const float*)d_in[22], (const float*)d_in[23],
        (const float*)d_in[25], (const float*)d_in[28], (const float*)d_in[27],
        Bp0, Bp1, Bp2, qwb3);

    const int gemm_grid = (N_NODES + 31) / 32;
    const int attn_grid = (N_NODES + 15) / 16;
    ushort_t* Bps[3] = { Bp0, Bp1, Bp2 };

    for (int l = 0; l < 3; l++){
        const float* bq = (const float*)d_in[3 + 9 * l + 1];
        const float* bk = (const float*)d_in[3 + 9 * l + 3];
        const float* bv = (const float*)d_in[3 + 9 * l + 5];
        const float* We = (const float*)d_in[3 + 9 * l + 6];
        const float* bs = (const float*)d_in[3 + 9 * l + 8];

        if (l == 0)
            gemm_mfma<256><<<gemm_grid, 320, 0, stream>>>(Xbf, Bps[l], bq, bk, bv, bs, qwb3 + 128 * l,
                                                          qbuf, kbf, vbf, sbuf, qwbuf, N_NODES);
        else
            gemm_mfma<128><<<gemm_grid, 320, 0, stream>>>(Hbf, Bps[l], bq, bk, bv, bs, qwb3 + 128 * l,
                                                          qbuf, kbf, vbf, sbuf, qwbuf, N_NODES);

        const float* gg = (l < 2) ? gln[l] : nullptr;
        const float* bb = (l < 2) ? beln[l] : nullptr;
        fused_attn_kernel<<<attn_grid, 256, 0, stream>>>(
            qbuf, qwbuf, kbf, vbf, sbuf, We, attr, attr_bf, perm_mode,
            rowptr, es, norder, acsr, a_out[l], gg, bb,
            (l < 2) ? nullptr : h_out, (l < 2) ? Hbf : nullptr, (l < 2) ? 1 : 0);
    }
}